// Round 3
// baseline (2345.311 us; speedup 1.0000x reference)
//
#include <hip/hip_runtime.h>
#include <float.h>

#define BB 128
#define N1 21
#define N2 4096
#define CC 256   // C (points2 channels)
#define LCH 256  // LC
#define HH 128   // H
#define KNN 64
#define KP 268   // LDS X row stride in f16 (256 + pad; bank stride 6 mod 32)

typedef _Float16 f16;
typedef f16 f16x4 __attribute__((ext_vector_type(4)));
typedef f16 f16x8 __attribute__((ext_vector_type(8)));
typedef float f32x4 __attribute__((ext_vector_type(4)));

// ---- workspace layout (float units) ----
static const size_t OFF_A1  = 0;                                   // [2688][256] f32
static const size_t OFF_KNN = OFF_A1 + (size_t)BB * N1 * 256;      // [2688][64] int
static const size_t OFF_W4T = OFF_KNN + (size_t)BB * N1 * KNN;     // [256][256] f32
static const size_t OFF_W5T = OFF_W4T + 65536;
static const size_t OFF_P1H = OFF_W5T + 65536;                     // each pack: 65536 f16 = 32768 f32
static const size_t OFF_P1L = OFF_P1H + 32768;
static const size_t OFF_P2H = OFF_P1L + 32768;
static const size_t OFF_P2L = OFF_P2H + 32768;
static const size_t OFF_P3H = OFF_P2L + 32768;
static const size_t OFF_P3L = OFF_P3H + 32768;

__device__ __forceinline__ float lrelu(float x) { return x > 0.f ? x : 0.1f * x; }

// fragment k-mapping kappa(lane,j) = 4*(lane>>4) + (j&3) + 16*(j>>2), used for BOTH
// A and B packing -> k-permutation cancels in the dot product.

// ---------------- kernel 0: weight pack/split ----------------
__device__ __forceinline__ void pack_one(int e, const float* __restrict__ w, int stride, int koff,
                                         f16* __restrict__ hi, f16* __restrict__ lo) {
  int j = e & 7, lane = (e >> 3) & 63, ntg = (e >> 9) & 15, ks = e >> 13;
  int n = ntg * 16 + (lane & 15);
  int k = ks * 32 + 4 * (lane >> 4) + (j & 3) + 16 * (j >> 2);
  float v = w[(size_t)n * stride + koff + k];
  f16 h = (f16)v;
  f16 l = (f16)(v - (float)h);
  hi[e] = h; lo[e] = l;
}

__global__ __launch_bounds__(256) void k_pack(
    const float* __restrict__ w1, const float* __restrict__ w2,
    const float* __restrict__ w3, const float* __restrict__ w4,
    const float* __restrict__ w5, float* __restrict__ ws) {
  int t = blockIdx.x * 256 + threadIdx.x;
  if (t < 131072) {   // W4T / W5T fp32 transpose
    int m = t >> 16, v = t & 65535;
    int c = v >> 8, o = v & 255;
    const float* src = m ? w5 : w4;
    float* dst = ws + (m ? OFF_W5T : OFF_W4T);
    dst[v] = src[o * 256 + c];
    return;
  }
  int u = t - 131072;
  if (u < 65536) { pack_one(u, w1, 387, 128, (f16*)(ws + OFF_P1H), (f16*)(ws + OFF_P1L)); return; }
  u -= 65536;
  if (u < 65536) { pack_one(u, w2, 256, 0, (f16*)(ws + OFF_P2H), (f16*)(ws + OFF_P2L)); return; }
  u -= 65536;
  if (u < 65536) { pack_one(u, w3, 256, 0, (f16*)(ws + OFF_P3H), (f16*)(ws + OFF_P3L)); return; }
}

// ---------------- kernel 1: biasfold -> A1 (p1-part of mlp layer 1 folded in) ----------------
__global__ __launch_bounds__(128) void k_biasfold(
    const float* __restrict__ points1,
    const float* __restrict__ w1, const float* __restrict__ bb1,
    const float* __restrict__ g1, const float* __restrict__ be1,
    const float* __restrict__ w2, const float* __restrict__ bb2,
    const float* __restrict__ g2, const float* __restrict__ be2,
    const float* __restrict__ w3, const float* __restrict__ bb3,
    const float* __restrict__ g3, const float* __restrict__ be3,
    const float* __restrict__ w1mlp,
    float* __restrict__ A1out) {
  int blk = blockIdx.x;
  int b = blk / N1, n = blk % N1;
  int t = threadIdx.x;
  __shared__ float x0[LCH], x1s[HH], x2s[HH], x3s[HH];
  const float bnS = 1.0f / sqrtf(1.0f + 1e-5f);

  x0[t]       = points1[((size_t)b * LCH + t) * N1 + n];
  x0[t + 128] = points1[((size_t)b * LCH + t + 128) * N1 + n];
  __syncthreads();
  {
    float acc = 0.f;
    const float* wr = w1 + (size_t)t * LCH;
    #pragma unroll 4
    for (int c = 0; c < LCH; c++) acc += wr[c] * x0[c];
    acc += bb1[t * N1 + n];
    acc = acc * (g1[t] * bnS) + be1[t];
    x1s[t] = lrelu(acc);
  }
  __syncthreads();
  {
    float acc = 0.f;
    const float* wr = w2 + (size_t)t * HH;
    #pragma unroll 4
    for (int c = 0; c < HH; c++) acc += wr[c] * x1s[c];
    acc += bb2[t * N1 + n];
    acc = acc * (g2[t] * bnS) + be2[t];
    x2s[t] = lrelu(acc);
  }
  __syncthreads();
  {
    float acc = 0.f;
    const float* wr = w3 + (size_t)t * HH;
    #pragma unroll 4
    for (int c = 0; c < HH; c++) acc += wr[c] * x2s[c];
    acc += bb3[t * N1 + n];
    acc = acc * (g3[t] * bnS) + be3[t];
    x3s[t] = lrelu(acc);
  }
  __syncthreads();
  // A1[n] = sum_{c<128} W1mlp[n][c] * p1[c]  (k-independent part of mlp layer 1)
  #pragma unroll
  for (int rep = 0; rep < 2; rep++) {
    int o = t + rep * 128;
    const float* wr = w1mlp + (size_t)o * 387;
    float acc = 0.f;
    #pragma unroll 4
    for (int c = 0; c < HH; c++) acc += wr[c] * x3s[c];
    A1out[(size_t)blk * 256 + o] = acc;
  }
}

// ---------------- kernel 2: kNN (unchanged, passing) ----------------
__global__ __launch_bounds__(256) void k_knn(
    const float* __restrict__ xyz1, const float* __restrict__ xyz2,
    int* __restrict__ knn) {
  int blk = blockIdx.x;
  int b = blk / N1, n = blk % N1;
  int t = threadIdx.x;
  __shared__ float dist[N2];
  __shared__ float wvv[4];
  __shared__ int wii[4];

  float ax = xyz1[((size_t)b * 3 + 0) * N1 + n];
  float ay = xyz1[((size_t)b * 3 + 1) * N1 + n];
  float az = xyz1[((size_t)b * 3 + 2) * N1 + n];
  float xx1 = ax * ax + ay * ay + az * az;
  const float* X = xyz2 + (size_t)b * 3 * N2;

  for (int i = 0; i < 16; i++) {
    int j = t + i * 256;
    float px = X[j], py = X[N2 + j], pz = X[2 * N2 + j];
    float xx2 = px * px + py * py + pz * pz;
    float dot = ax * px + ay * py + az * pz;
    dist[j] = (xx1 + xx2) - 2.0f * dot;
  }
  __syncthreads();

  int* out = knn + (size_t)blk * KNN;
  for (int it = 0; it < KNN; it++) {
    float best = FLT_MAX;
    int bi = N2;
    for (int i = 0; i < 16; i++) {
      int j = t + i * 256;
      float v = dist[j];
      if (v < best) { best = v; bi = j; }
    }
    for (int off = 32; off; off >>= 1) {
      float ov = __shfl_down(best, off);
      int oi = __shfl_down(bi, off);
      if (ov < best || (ov == best && oi < bi)) { best = ov; bi = oi; }
    }
    int w = t >> 6;
    if ((t & 63) == 0) { wvv[w] = best; wii[w] = bi; }
    __syncthreads();
    if (t == 0) {
      float bv = wvv[0]; int bj = wii[0];
      for (int q = 1; q < 4; q++)
        if (wvv[q] < bv || (wvv[q] == bv && wii[q] < bj)) { bv = wvv[q]; bj = wii[q]; }
      out[it] = bj;
      dist[bj] = FLT_MAX;
    }
    __syncthreads();
  }
}

// ---------------- MFMA layer: M=32 rows x N=64 cols per wave, split-fp16, K=256 ----------------
__device__ __forceinline__ void run_layer32(
    const f16* __restrict__ BH, const f16* __restrict__ BL,
    const f16* Xh, const f16* Xl,
    int w, int lane, int r16, int g, f32x4 acc[2][4]) {
  for (int ks = 0; ks < 8; ks++) {
    f16x8 Bh[4], Bl[4];
    #pragma unroll
    for (int nt = 0; nt < 4; nt++) {
      size_t fi = ((size_t)((ks * 16 + w * 4 + nt) * 64 + lane)) * 8;
      Bh[nt] = *(const f16x8*)(BH + fi);
      Bl[nt] = *(const f16x8*)(BL + fi);
    }
    int k0 = ks * 32 + 4 * g;
    f16x8 Ah[2], Al[2];
    #pragma unroll
    for (int mt = 0; mt < 2; mt++) {
      int base = (mt * 16 + r16) * KP + k0;
      f16x4 h0 = *(const f16x4*)(Xh + base);
      f16x4 h1 = *(const f16x4*)(Xh + base + 16);
      f16x4 l0 = *(const f16x4*)(Xl + base);
      f16x4 l1 = *(const f16x4*)(Xl + base + 16);
      Ah[mt] = __builtin_shufflevector(h0, h1, 0, 1, 2, 3, 4, 5, 6, 7);
      Al[mt] = __builtin_shufflevector(l0, l1, 0, 1, 2, 3, 4, 5, 6, 7);
    }
    #pragma unroll
    for (int mt = 0; mt < 2; mt++)
      #pragma unroll
      for (int nt = 0; nt < 4; nt++) {
        acc[mt][nt] = __builtin_amdgcn_mfma_f32_16x16x32_f16(Ah[mt], Bh[nt], acc[mt][nt], 0, 0, 0);
        acc[mt][nt] = __builtin_amdgcn_mfma_f32_16x16x32_f16(Ah[mt], Bl[nt], acc[mt][nt], 0, 0, 0);
        acc[mt][nt] = __builtin_amdgcn_mfma_f32_16x16x32_f16(Al[mt], Bh[nt], acc[mt][nt], 0, 0, 0);
      }
  }
}

__device__ __forceinline__ void writeback_act(
    f32x4 acc[2][4], const float* __restrict__ bias,
    f16* Xh, f16* Xl, int w, int r16, int g) {
  #pragma unroll
  for (int nt = 0; nt < 4; nt++) {
    int nl = w * 64 + nt * 16 + r16;
    float bv = bias[nl];
    #pragma unroll
    for (int mt = 0; mt < 2; mt++)
      #pragma unroll
      for (int j = 0; j < 4; j++) {
        int m = mt * 16 + 4 * g + j;
        float y = lrelu(acc[mt][nt][j] + bv);
        f16 h = (f16)y;
        Xh[m * KP + nl] = h;
        Xl[m * KP + nl] = (f16)(y - (float)h);
      }
  }
}

// ---------------- kernel 3: fused gather + MFMA MLP + maxpool + mlp2 + regress ----------------
__global__ __launch_bounds__(256, 4) void k_fused3(
    const float* __restrict__ xyz1, const float* __restrict__ xyz2,
    const float* __restrict__ points2,
    const float* __restrict__ A1ws, const int* __restrict__ knn,
    const float* __restrict__ w1mlp,
    const f16* __restrict__ P1H, const f16* __restrict__ P1L,
    const f16* __restrict__ P2H, const f16* __restrict__ P2L,
    const f16* __restrict__ P3H, const f16* __restrict__ P3L,
    const float* __restrict__ b1, const float* __restrict__ b2,
    const float* __restrict__ b3,
    const float* __restrict__ W4T, const float* __restrict__ W5T,
    const float* __restrict__ regw, const float* __restrict__ regb,
    float* __restrict__ out) {
  int bid = blockIdx.x;
  // XCD swizzle: all 21 n1-blocks of a batch land on one XCD (2688 = 8*336)
  int xcd = bid & 7, slot = bid >> 3;
  int b = xcd * 16 + slot / 21;
  int n1 = slot % 21;
  int row = b * N1 + n1;

  int t = threadIdx.x;
  int lane = t & 63, w = t >> 6;
  int r16 = lane & 15, g = lane >> 4;

  __shared__ __align__(16) f16 Xhi[32 * KP];
  __shared__ __align__(16) f16 Xlo[32 * KP];
  __shared__ float dirs[32][3];
  __shared__ int idxs[KNN];
  __shared__ float x1p[3];

  if (t < KNN) idxs[t] = knn[(size_t)row * KNN + t];
  if (t < 3) x1p[t] = xyz1[((size_t)b * 3 + t) * N1 + n1];
  __syncthreads();

  // per-lane constants: A1 + dir-part weights for this lane's 4 output columns
  float a1v[4], wd0[4], wd1[4], wd2[4];
  #pragma unroll
  for (int nt = 0; nt < 4; nt++) {
    int n = w * 64 + nt * 16 + r16;
    a1v[nt] = A1ws[(size_t)row * 256 + n];
    wd0[nt] = w1mlp[(size_t)n * 387 + 384];
    wd1[nt] = w1mlp[(size_t)n * 387 + 385];
    wd2[nt] = w1mlp[(size_t)n * 387 + 386];
  }

  float poolm[4] = {-FLT_MAX, -FLT_MAX, -FLT_MAX, -FLT_MAX};
  const float* p2b = points2 + (size_t)b * CC * N2;
  const float* x2b = xyz2 + (size_t)b * 3 * N2;

  for (int pass = 0; pass < 2; pass++) {
    // dirs for this pass's 32 neighbors
    if (t < 32) {
      int id = idxs[pass * 32 + t];
      #pragma unroll
      for (int d = 0; d < 3; d++)
        dirs[t][d] = x2b[(size_t)d * N2 + id] - x1p[d];
    }
    // gather g2: thread t -> row r = t>>3, channels c = (t&7) + 8i
    {
      int r = t >> 3, q = t & 7;
      int id = idxs[pass * 32 + r];
      const float* src = p2b + id;
      #pragma unroll 4
      for (int i = 0; i < 32; i++) {
        int c = q + 8 * i;
        float v = src[(size_t)c * N2];
        f16 h = (f16)v;
        Xhi[r * KP + c] = h;
        Xlo[r * KP + c] = (f16)(v - (float)h);
      }
    }
    __syncthreads();

    f32x4 acc[2][4];
    // ---- layer 1 (K=256 over g2), acc init = A1[n] + W1[n][384:387]·dir[m] ----
    #pragma unroll
    for (int mt = 0; mt < 2; mt++)
      #pragma unroll
      for (int nt = 0; nt < 4; nt++)
        #pragma unroll
        for (int j = 0; j < 4; j++) {
          int m = mt * 16 + 4 * g + j;
          acc[mt][nt][j] = a1v[nt] + wd0[nt] * dirs[m][0]
                                   + wd1[nt] * dirs[m][1]
                                   + wd2[nt] * dirs[m][2];
        }
    run_layer32(P1H, P1L, Xhi, Xlo, w, lane, r16, g, acc);
    __syncthreads();
    writeback_act(acc, b1, Xhi, Xlo, w, r16, g);
    __syncthreads();

    // ---- layer 2 ----
    #pragma unroll
    for (int mt = 0; mt < 2; mt++)
      #pragma unroll
      for (int nt = 0; nt < 4; nt++) acc[mt][nt] = (f32x4){0.f, 0.f, 0.f, 0.f};
    run_layer32(P2H, P2L, Xhi, Xlo, w, lane, r16, g, acc);
    __syncthreads();
    writeback_act(acc, b2, Xhi, Xlo, w, r16, g);
    __syncthreads();

    // ---- layer 3 + maxpool over this pass's 32 rows (bias/lrelu deferred) ----
    #pragma unroll
    for (int mt = 0; mt < 2; mt++)
      #pragma unroll
      for (int nt = 0; nt < 4; nt++) acc[mt][nt] = (f32x4){0.f, 0.f, 0.f, 0.f};
    run_layer32(P3H, P3L, Xhi, Xlo, w, lane, r16, g, acc);
    #pragma unroll
    for (int nt = 0; nt < 4; nt++) {
      float m = -FLT_MAX;
      #pragma unroll
      for (int mt = 0; mt < 2; mt++)
        #pragma unroll
        for (int j = 0; j < 4; j++) m = fmaxf(m, acc[mt][nt][j]);
      m = fmaxf(m, __shfl_xor(m, 16));
      m = fmaxf(m, __shfl_xor(m, 32));
      poolm[nt] = fmaxf(poolm[nt], m);
    }
    __syncthreads();   // X free for next pass / tail
  }

  // ---- tail: pooled -> mlp2 -> regress (fp32), X arena reused as float buffer ----
  float* fb = (float*)Xhi;   // [0:256) pooled, [256:512) z1, [512:768) z2
  if (g == 0) {
    #pragma unroll
    for (int nt = 0; nt < 4; nt++) {
      int n = w * 64 + nt * 16 + r16;
      fb[n] = lrelu(poolm[nt] + b3[n]);   // bias+lrelu commute with max
    }
  }
  __syncthreads();
  {
    float a = 0.f;
    #pragma unroll 4
    for (int c = 0; c < 256; c++) a += W4T[(size_t)c * 256 + t] * fb[c];
    fb[256 + t] = lrelu(a);
  }
  __syncthreads();
  {
    float a = 0.f;
    #pragma unroll 4
    for (int c = 0; c < 256; c++) a += W5T[(size_t)c * 256 + t] * fb[256 + c];
    fb[512 + t] = lrelu(a);
  }
  __syncthreads();
  if (t < 192) {
    int o = t >> 6;
    float a = 0.f;
    #pragma unroll
    for (int i = 0; i < 4; i++) {
      int c = (t & 63) + 64 * i;
      a += regw[o * 256 + c] * fb[512 + c];
    }
    #pragma unroll
    for (int off = 32; off; off >>= 1) a += __shfl_xor(a, off);
    if ((t & 63) == 0) out[((size_t)b * 3 + o) * N1 + n1] = a + regb[o];
  }
}

extern "C" void kernel_launch(void* const* d_in, const int* in_sizes, int n_in,
                              void* d_out, int out_size, void* d_ws, size_t ws_size,
                              hipStream_t stream) {
  const float* xyz1    = (const float*)d_in[0];
  const float* xyz2    = (const float*)d_in[1];
  const float* points1 = (const float*)d_in[2];
  const float* points2 = (const float*)d_in[3];
  const float* bf_w1 = (const float*)d_in[4],  *bf_b1 = (const float*)d_in[5];
  const float* bf_g1 = (const float*)d_in[6],  *bf_e1 = (const float*)d_in[7];
  const float* bf_w2 = (const float*)d_in[8],  *bf_b2 = (const float*)d_in[9];
  const float* bf_g2 = (const float*)d_in[10], *bf_e2 = (const float*)d_in[11];
  const float* bf_w3 = (const float*)d_in[12], *bf_b3 = (const float*)d_in[13];
  const float* bf_g3 = (const float*)d_in[14], *bf_e3 = (const float*)d_in[15];
  const float* mlp_w1 = (const float*)d_in[16], *mlp_b1 = (const float*)d_in[17];
  const float* mlp_w2 = (const float*)d_in[18], *mlp_b2 = (const float*)d_in[19];
  const float* mlp_w3 = (const float*)d_in[20], *mlp_b3 = (const float*)d_in[21];
  const float* mlp2_w1 = (const float*)d_in[22], *mlp2_w2 = (const float*)d_in[23];
  const float* reg_w = (const float*)d_in[24], *reg_b = (const float*)d_in[25];

  float* ws  = (float*)d_ws;
  float* A1  = ws + OFF_A1;
  int*   knn = (int*)(ws + OFF_KNN);

  float* out = (float*)d_out;
  int rows = BB * N1;  // 2688

  k_pack<<<1280, 256, 0, stream>>>(mlp_w1, mlp_w2, mlp_w3, mlp2_w1, mlp2_w2, ws);
  k_biasfold<<<rows, 128, 0, stream>>>(points1,
      bf_w1, bf_b1, bf_g1, bf_e1,
      bf_w2, bf_b2, bf_g2, bf_e2,
      bf_w3, bf_b3, bf_g3, bf_e3, mlp_w1, A1);
  k_knn<<<rows, 256, 0, stream>>>(xyz1, xyz2, knn);
  k_fused3<<<rows, 256, 0, stream>>>(xyz1, xyz2, points2, A1, knn, mlp_w1,
      (const f16*)(ws + OFF_P1H), (const f16*)(ws + OFF_P1L),
      (const f16*)(ws + OFF_P2H), (const f16*)(ws + OFF_P2L),
      (const f16*)(ws + OFF_P3H), (const f16*)(ws + OFF_P3L),
      mlp_b1, mlp_b2, mlp_b3,
      ws + OFF_W4T, ws + OFF_W5T, reg_w, reg_b, out);
}

// Round 4
// 2316.851 us; speedup vs baseline: 1.0123x; 1.0123x over previous
//
#include <hip/hip_runtime.h>
#include <float.h>

#define BB 128
#define N1 21
#define N2 4096
#define CC 256   // C (points2 channels)
#define LCH 256  // LC
#define HH 128   // H
#define KNN 64
#define KP 268   // LDS X row stride in f16 (256 + pad; bank stride 6 mod 32)

typedef _Float16 f16;
typedef f16 f16x4 __attribute__((ext_vector_type(4)));
typedef f16 f16x8 __attribute__((ext_vector_type(8)));
typedef float f32x4 __attribute__((ext_vector_type(4)));

// ---- workspace layout (float units) ----
static const size_t OFF_A1  = 0;                                   // [2688][256] f32
static const size_t OFF_KNN = OFF_A1 + (size_t)BB * N1 * 256;      // [2688][64] int
static const size_t OFF_W4T = OFF_KNN + (size_t)BB * N1 * KNN;     // [256][256] f32
static const size_t OFF_W5T = OFF_W4T + 65536;
static const size_t OFF_P1H = OFF_W5T + 65536;                     // each pack: 65536 f16 = 32768 f32
static const size_t OFF_P1L = OFF_P1H + 32768;
static const size_t OFF_P2H = OFF_P1L + 32768;
static const size_t OFF_P2L = OFF_P2H + 32768;
static const size_t OFF_P3H = OFF_P2L + 32768;
static const size_t OFF_P3L = OFF_P3H + 32768;

__device__ __forceinline__ float lrelu(float x) { return x > 0.f ? x : 0.1f * x; }

// fragment k-mapping kappa(lane,j) = 4*(lane>>4) + (j&3) + 16*(j>>2), used for BOTH
// A and B packing -> k-permutation cancels in the dot product.

// ---------------- kernel 0: weight pack/split ----------------
__device__ __forceinline__ void pack_one(int e, const float* __restrict__ w, int stride, int koff,
                                         f16* __restrict__ hi, f16* __restrict__ lo) {
  int j = e & 7, lane = (e >> 3) & 63, ntg = (e >> 9) & 15, ks = e >> 13;
  int n = ntg * 16 + (lane & 15);
  int k = ks * 32 + 4 * (lane >> 4) + (j & 3) + 16 * (j >> 2);
  float v = w[(size_t)n * stride + koff + k];
  f16 h = (f16)v;
  f16 l = (f16)(v - (float)h);
  hi[e] = h; lo[e] = l;
}

__global__ __launch_bounds__(256) void k_pack(
    const float* __restrict__ w1, const float* __restrict__ w2,
    const float* __restrict__ w3, const float* __restrict__ w4,
    const float* __restrict__ w5, float* __restrict__ ws) {
  int t = blockIdx.x * 256 + threadIdx.x;
  if (t < 131072) {   // W4T / W5T fp32 transpose
    int m = t >> 16, v = t & 65535;
    int c = v >> 8, o = v & 255;
    const float* src = m ? w5 : w4;
    float* dst = ws + (m ? OFF_W5T : OFF_W4T);
    dst[v] = src[o * 256 + c];
    return;
  }
  int u = t - 131072;
  if (u < 65536) { pack_one(u, w1, 387, 128, (f16*)(ws + OFF_P1H), (f16*)(ws + OFF_P1L)); return; }
  u -= 65536;
  if (u < 65536) { pack_one(u, w2, 256, 0, (f16*)(ws + OFF_P2H), (f16*)(ws + OFF_P2L)); return; }
  u -= 65536;
  if (u < 65536) { pack_one(u, w3, 256, 0, (f16*)(ws + OFF_P3H), (f16*)(ws + OFF_P3L)); return; }
}

// ---------------- kernel 1: biasfold -> A1 (p1-part of mlp layer 1 folded in) ----------------
__global__ __launch_bounds__(128) void k_biasfold(
    const float* __restrict__ points1,
    const float* __restrict__ w1, const float* __restrict__ bb1,
    const float* __restrict__ g1, const float* __restrict__ be1,
    const float* __restrict__ w2, const float* __restrict__ bb2,
    const float* __restrict__ g2, const float* __restrict__ be2,
    const float* __restrict__ w3, const float* __restrict__ bb3,
    const float* __restrict__ g3, const float* __restrict__ be3,
    const float* __restrict__ w1mlp,
    float* __restrict__ A1out) {
  int blk = blockIdx.x;
  int b = blk / N1, n = blk % N1;
  int t = threadIdx.x;
  __shared__ float x0[LCH], x1s[HH], x2s[HH], x3s[HH];
  const float bnS = 1.0f / sqrtf(1.0f + 1e-5f);

  x0[t]       = points1[((size_t)b * LCH + t) * N1 + n];
  x0[t + 128] = points1[((size_t)b * LCH + t + 128) * N1 + n];
  __syncthreads();
  {
    float acc = 0.f;
    const float* wr = w1 + (size_t)t * LCH;
    #pragma unroll 4
    for (int c = 0; c < LCH; c++) acc += wr[c] * x0[c];
    acc += bb1[t * N1 + n];
    acc = acc * (g1[t] * bnS) + be1[t];
    x1s[t] = lrelu(acc);
  }
  __syncthreads();
  {
    float acc = 0.f;
    const float* wr = w2 + (size_t)t * HH;
    #pragma unroll 4
    for (int c = 0; c < HH; c++) acc += wr[c] * x1s[c];
    acc += bb2[t * N1 + n];
    acc = acc * (g2[t] * bnS) + be2[t];
    x2s[t] = lrelu(acc);
  }
  __syncthreads();
  {
    float acc = 0.f;
    const float* wr = w3 + (size_t)t * HH;
    #pragma unroll 4
    for (int c = 0; c < HH; c++) acc += wr[c] * x2s[c];
    acc += bb3[t * N1 + n];
    acc = acc * (g3[t] * bnS) + be3[t];
    x3s[t] = lrelu(acc);
  }
  __syncthreads();
  // A1[n] = sum_{c<128} W1mlp[n][c] * p1[c]  (k-independent part of mlp layer 1)
  #pragma unroll
  for (int rep = 0; rep < 2; rep++) {
    int o = t + rep * 128;
    const float* wr = w1mlp + (size_t)o * 387;
    float acc = 0.f;
    #pragma unroll 4
    for (int c = 0; c < HH; c++) acc += wr[c] * x3s[c];
    A1out[(size_t)blk * 256 + o] = acc;
  }
}

// ---------------- kernel 2: kNN (unchanged, passing) ----------------
__global__ __launch_bounds__(256) void k_knn(
    const float* __restrict__ xyz1, const float* __restrict__ xyz2,
    int* __restrict__ knn) {
  int blk = blockIdx.x;
  int b = blk / N1, n = blk % N1;
  int t = threadIdx.x;
  __shared__ float dist[N2];
  __shared__ float wvv[4];
  __shared__ int wii[4];

  float ax = xyz1[((size_t)b * 3 + 0) * N1 + n];
  float ay = xyz1[((size_t)b * 3 + 1) * N1 + n];
  float az = xyz1[((size_t)b * 3 + 2) * N1 + n];
  float xx1 = ax * ax + ay * ay + az * az;
  const float* X = xyz2 + (size_t)b * 3 * N2;

  for (int i = 0; i < 16; i++) {
    int j = t + i * 256;
    float px = X[j], py = X[N2 + j], pz = X[2 * N2 + j];
    float xx2 = px * px + py * py + pz * pz;
    float dot = ax * px + ay * py + az * pz;
    dist[j] = (xx1 + xx2) - 2.0f * dot;
  }
  __syncthreads();

  int* out = knn + (size_t)blk * KNN;
  for (int it = 0; it < KNN; it++) {
    float best = FLT_MAX;
    int bi = N2;
    for (int i = 0; i < 16; i++) {
      int j = t + i * 256;
      float v = dist[j];
      if (v < best) { best = v; bi = j; }
    }
    for (int off = 32; off; off >>= 1) {
      float ov = __shfl_down(best, off);
      int oi = __shfl_down(bi, off);
      if (ov < best || (ov == best && oi < bi)) { best = ov; bi = oi; }
    }
    int w = t >> 6;
    if ((t & 63) == 0) { wvv[w] = best; wii[w] = bi; }
    __syncthreads();
    if (t == 0) {
      float bv = wvv[0]; int bj = wii[0];
      for (int q = 1; q < 4; q++)
        if (wvv[q] < bv || (wvv[q] == bv && wii[q] < bj)) { bv = wvv[q]; bj = wii[q]; }
      out[it] = bj;
      dist[bj] = FLT_MAX;
    }
    __syncthreads();
  }
}

// ---------------- MFMA layer: M=32 x N=64 per wave, split-fp16, K=256 ----------------
// n-tiles processed in PAIRS to cap live B-fragment registers (~16 instead of 32).
__device__ __forceinline__ void run_layer32(
    const f16* __restrict__ BH, const f16* __restrict__ BL,
    const f16* Xh, const f16* Xl,
    int w, int lane, int r16, int g, f32x4 acc[2][4]) {
  for (int ks = 0; ks < 8; ks++) {
    int k0 = ks * 32 + 4 * g;
    f16x8 Ah[2], Al[2];
    #pragma unroll
    for (int mt = 0; mt < 2; mt++) {
      int base = (mt * 16 + r16) * KP + k0;
      f16x4 h0 = *(const f16x4*)(Xh + base);
      f16x4 h1 = *(const f16x4*)(Xh + base + 16);
      f16x4 l0 = *(const f16x4*)(Xl + base);
      f16x4 l1 = *(const f16x4*)(Xl + base + 16);
      Ah[mt] = __builtin_shufflevector(h0, h1, 0, 1, 2, 3, 4, 5, 6, 7);
      Al[mt] = __builtin_shufflevector(l0, l1, 0, 1, 2, 3, 4, 5, 6, 7);
    }
    #pragma unroll
    for (int half = 0; half < 2; half++) {
      f16x8 Bh[2], Bl[2];
      #pragma unroll
      for (int p = 0; p < 2; p++) {
        int nt = half * 2 + p;
        size_t fi = ((size_t)((ks * 16 + w * 4 + nt) * 64 + lane)) * 8;
        Bh[p] = *(const f16x8*)(BH + fi);
        Bl[p] = *(const f16x8*)(BL + fi);
      }
      #pragma unroll
      for (int mt = 0; mt < 2; mt++)
        #pragma unroll
        for (int p = 0; p < 2; p++) {
          int nt = half * 2 + p;
          acc[mt][nt] = __builtin_amdgcn_mfma_f32_16x16x32_f16(Ah[mt], Bh[p], acc[mt][nt], 0, 0, 0);
          acc[mt][nt] = __builtin_amdgcn_mfma_f32_16x16x32_f16(Ah[mt], Bl[p], acc[mt][nt], 0, 0, 0);
          acc[mt][nt] = __builtin_amdgcn_mfma_f32_16x16x32_f16(Al[mt], Bh[p], acc[mt][nt], 0, 0, 0);
        }
    }
  }
}

__device__ __forceinline__ void writeback_act(
    f32x4 acc[2][4], const float* __restrict__ bias,
    f16* Xh, f16* Xl, int w, int r16, int g) {
  #pragma unroll
  for (int nt = 0; nt < 4; nt++) {
    int nl = w * 64 + nt * 16 + r16;
    float bv = bias[nl];
    #pragma unroll
    for (int mt = 0; mt < 2; mt++)
      #pragma unroll
      for (int j = 0; j < 4; j++) {
        int m = mt * 16 + 4 * g + j;
        float y = lrelu(acc[mt][nt][j] + bv);
        f16 h = (f16)y;
        Xh[m * KP + nl] = h;
        Xl[m * KP + nl] = (f16)(y - (float)h);
      }
  }
}

// ---------------- kernel 3: fused gather + MFMA MLP + maxpool + mlp2 + regress ----------------
__global__ __launch_bounds__(256, 3) void k_fused4(
    const float* __restrict__ xyz1, const float* __restrict__ xyz2,
    const float* __restrict__ points2,
    const float* __restrict__ A1ws, const int* __restrict__ knn,
    const float* __restrict__ w1mlp,
    const f16* __restrict__ P1H, const f16* __restrict__ P1L,
    const f16* __restrict__ P2H, const f16* __restrict__ P2L,
    const f16* __restrict__ P3H, const f16* __restrict__ P3L,
    const float* __restrict__ b1, const float* __restrict__ b2,
    const float* __restrict__ b3,
    const float* __restrict__ W4T, const float* __restrict__ W5T,
    const float* __restrict__ regw, const float* __restrict__ regb,
    float* __restrict__ out) {
  int bid = blockIdx.x;
  // XCD swizzle: all 21 n1-blocks of a batch land on one XCD (2688 = 8*336)
  int xcd = bid & 7, slot = bid >> 3;
  int b = xcd * 16 + slot / 21;
  int n1 = slot % 21;
  int row = b * N1 + n1;

  int t = threadIdx.x;
  int lane = t & 63, w = t >> 6;
  int r16 = lane & 15, g = lane >> 4;

  __shared__ __align__(16) f16 Xhi[32 * KP];
  __shared__ __align__(16) f16 Xlo[32 * KP];
  __shared__ float dirs[32][3];
  __shared__ int idxs[KNN];
  __shared__ float x1p[3];

  if (t < KNN) idxs[t] = knn[(size_t)row * KNN + t];
  if (t < 3) x1p[t] = xyz1[((size_t)b * 3 + t) * N1 + n1];
  __syncthreads();

  // per-lane constants: A1 + dir-part weights for this lane's 4 output columns
  float a1v[4], wd0[4], wd1[4], wd2[4];
  #pragma unroll
  for (int nt = 0; nt < 4; nt++) {
    int n = w * 64 + nt * 16 + r16;
    a1v[nt] = A1ws[(size_t)row * 256 + n];
    wd0[nt] = w1mlp[(size_t)n * 387 + 384];
    wd1[nt] = w1mlp[(size_t)n * 387 + 385];
    wd2[nt] = w1mlp[(size_t)n * 387 + 386];
  }

  float poolm[4] = {-FLT_MAX, -FLT_MAX, -FLT_MAX, -FLT_MAX};
  const float* p2b = points2 + (size_t)b * CC * N2;
  const float* x2b = xyz2 + (size_t)b * 3 * N2;

  for (int pass = 0; pass < 2; pass++) {
    // dirs for this pass's 32 neighbors
    if (t < 32) {
      int id = idxs[pass * 32 + t];
      #pragma unroll
      for (int d = 0; d < 3; d++)
        dirs[t][d] = x2b[(size_t)d * N2 + id] - x1p[d];
    }
    // gather g2: thread t -> row r = t>>3, channels c = (t&7) + 8i
    {
      int r = t >> 3, q = t & 7;
      int id = idxs[pass * 32 + r];
      const float* src = p2b + id;
      #pragma unroll 4
      for (int i = 0; i < 32; i++) {
        int c = q + 8 * i;
        float v = src[(size_t)c * N2];
        f16 h = (f16)v;
        Xhi[r * KP + c] = h;
        Xlo[r * KP + c] = (f16)(v - (float)h);
      }
    }
    __syncthreads();

    f32x4 acc[2][4];
    // ---- layer 1 (K=256 over g2), acc init = A1[n] + W1[n][384:387]·dir[m] ----
    #pragma unroll
    for (int mt = 0; mt < 2; mt++)
      #pragma unroll
      for (int nt = 0; nt < 4; nt++)
        #pragma unroll
        for (int j = 0; j < 4; j++) {
          int m = mt * 16 + 4 * g + j;
          acc[mt][nt][j] = a1v[nt] + wd0[nt] * dirs[m][0]
                                   + wd1[nt] * dirs[m][1]
                                   + wd2[nt] * dirs[m][2];
        }
    run_layer32(P1H, P1L, Xhi, Xlo, w, lane, r16, g, acc);
    __syncthreads();
    writeback_act(acc, b1, Xhi, Xlo, w, r16, g);
    __syncthreads();

    // ---- layer 2 ----
    #pragma unroll
    for (int mt = 0; mt < 2; mt++)
      #pragma unroll
      for (int nt = 0; nt < 4; nt++) acc[mt][nt] = (f32x4){0.f, 0.f, 0.f, 0.f};
    run_layer32(P2H, P2L, Xhi, Xlo, w, lane, r16, g, acc);
    __syncthreads();
    writeback_act(acc, b2, Xhi, Xlo, w, r16, g);
    __syncthreads();

    // ---- layer 3 + maxpool over this pass's 32 rows (bias/lrelu deferred) ----
    #pragma unroll
    for (int mt = 0; mt < 2; mt++)
      #pragma unroll
      for (int nt = 0; nt < 4; nt++) acc[mt][nt] = (f32x4){0.f, 0.f, 0.f, 0.f};
    run_layer32(P3H, P3L, Xhi, Xlo, w, lane, r16, g, acc);
    #pragma unroll
    for (int nt = 0; nt < 4; nt++) {
      float m = -FLT_MAX;
      #pragma unroll
      for (int mt = 0; mt < 2; mt++)
        #pragma unroll
        for (int j = 0; j < 4; j++) m = fmaxf(m, acc[mt][nt][j]);
      m = fmaxf(m, __shfl_xor(m, 16));
      m = fmaxf(m, __shfl_xor(m, 32));
      poolm[nt] = fmaxf(poolm[nt], m);
    }
    __syncthreads();   // X free for next pass / tail
  }

  // ---- tail: pooled -> mlp2 -> regress (fp32), X arena reused as float buffer ----
  float* fb = (float*)Xhi;   // [0:256) pooled, [256:512) z1, [512:768) z2
  if (g == 0) {
    #pragma unroll
    for (int nt = 0; nt < 4; nt++) {
      int n = w * 64 + nt * 16 + r16;
      fb[n] = lrelu(poolm[nt] + b3[n]);   // bias+lrelu commute with max
    }
  }
  __syncthreads();
  {
    float a = 0.f;
    #pragma unroll 4
    for (int c = 0; c < 256; c++) a += W4T[(size_t)c * 256 + t] * fb[c];
    fb[256 + t] = lrelu(a);
  }
  __syncthreads();
  {
    float a = 0.f;
    #pragma unroll 4
    for (int c = 0; c < 256; c++) a += W5T[(size_t)c * 256 + t] * fb[256 + c];
    fb[512 + t] = lrelu(a);
  }
  __syncthreads();
  if (t < 192) {
    int o = t >> 6;
    float a = 0.f;
    #pragma unroll
    for (int i = 0; i < 4; i++) {
      int c = (t & 63) + 64 * i;
      a += regw[o * 256 + c] * fb[512 + c];
    }
    #pragma unroll
    for (int off = 32; off; off >>= 1) a += __shfl_xor(a, off);
    if ((t & 63) == 0) out[((size_t)b * 3 + o) * N1 + n1] = a + regb[o];
  }
}

extern "C" void kernel_launch(void* const* d_in, const int* in_sizes, int n_in,
                              void* d_out, int out_size, void* d_ws, size_t ws_size,
                              hipStream_t stream) {
  const float* xyz1    = (const float*)d_in[0];
  const float* xyz2    = (const float*)d_in[1];
  const float* points1 = (const float*)d_in[2];
  const float* points2 = (const float*)d_in[3];
  const float* bf_w1 = (const float*)d_in[4],  *bf_b1 = (const float*)d_in[5];
  const float* bf_g1 = (const float*)d_in[6],  *bf_e1 = (const float*)d_in[7];
  const float* bf_w2 = (const float*)d_in[8],  *bf_b2 = (const float*)d_in[9];
  const float* bf_g2 = (const float*)d_in[10], *bf_e2 = (const float*)d_in[11];
  const float* bf_w3 = (const float*)d_in[12], *bf_b3 = (const float*)d_in[13];
  const float* bf_g3 = (const float*)d_in[14], *bf_e3 = (const float*)d_in[15];
  const float* mlp_w1 = (const float*)d_in[16], *mlp_b1 = (const float*)d_in[17];
  const float* mlp_w2 = (const float*)d_in[18], *mlp_b2 = (const float*)d_in[19];
  const float* mlp_w3 = (const float*)d_in[20], *mlp_b3 = (const float*)d_in[21];
  const float* mlp2_w1 = (const float*)d_in[22], *mlp2_w2 = (const float*)d_in[23];
  const float* reg_w = (const float*)d_in[24], *reg_b = (const float*)d_in[25];

  float* ws  = (float*)d_ws;
  float* A1  = ws + OFF_A1;
  int*   knn = (int*)(ws + OFF_KNN);

  float* out = (float*)d_out;
  int rows = BB * N1;  // 2688

  k_pack<<<1280, 256, 0, stream>>>(mlp_w1, mlp_w2, mlp_w3, mlp2_w1, mlp2_w2, ws);
  k_biasfold<<<rows, 128, 0, stream>>>(points1,
      bf_w1, bf_b1, bf_g1, bf_e1,
      bf_w2, bf_b2, bf_g2, bf_e2,
      bf_w3, bf_b3, bf_g3, bf_e3, mlp_w1, A1);
  k_knn<<<rows, 256, 0, stream>>>(xyz1, xyz2, knn);
  k_fused4<<<rows, 256, 0, stream>>>(xyz1, xyz2, points2, A1, knn, mlp_w1,
      (const f16*)(ws + OFF_P1H), (const f16*)(ws + OFF_P1L),
      (const f16*)(ws + OFF_P2H), (const f16*)(ws + OFF_P2L),
      (const f16*)(ws + OFF_P3H), (const f16*)(ws + OFF_P3L),
      mlp_b1, mlp_b2, mlp_b3,
      ws + OFF_W4T, ws + OFF_W5T, reg_w, reg_b, out);
}

// Round 5
// 1948.138 us; speedup vs baseline: 1.2039x; 1.1893x over previous
//
#include <hip/hip_runtime.h>
#include <float.h>

#define BB 128
#define N1 21
#define N2 4096
#define CC 256   // C (points2 channels)
#define LCH 256  // LC
#define HH 128   // H
#define KNN 64
#define KP 268   // LDS X row stride in f16 (256 + pad; bank stride 6 mod 32)

typedef _Float16 f16;
typedef f16 f16x4 __attribute__((ext_vector_type(4)));
typedef f16 f16x8 __attribute__((ext_vector_type(8)));
typedef float f32x4 __attribute__((ext_vector_type(4)));

// ---- workspace layout (float units) ----
static const size_t OFF_A1  = 0;                                   // [2688][256] f32
static const size_t OFF_KNN = OFF_A1 + (size_t)BB * N1 * 256;      // [2688][64] int
static const size_t OFF_W4T = OFF_KNN + (size_t)BB * N1 * KNN;     // [256][256] f32
static const size_t OFF_W5T = OFF_W4T + 65536;
static const size_t OFF_P1H = OFF_W5T + 65536;                     // each pack: 65536 f16 = 32768 f32
static const size_t OFF_P1L = OFF_P1H + 32768;
static const size_t OFF_P2H = OFF_P1L + 32768;
static const size_t OFF_P2L = OFF_P2H + 32768;
static const size_t OFF_P3H = OFF_P2L + 32768;
static const size_t OFF_P3L = OFF_P3H + 32768;

__device__ __forceinline__ float lrelu(float x) { return x > 0.f ? x : 0.1f * x; }

// fragment k-mapping kappa(lane,j) = 4*(lane>>4) + (j&3) + 16*(j>>2), used for BOTH
// A and B packing -> k-permutation cancels in the dot product.

// ---------------- kernel 0: weight pack/split ----------------
__device__ __forceinline__ void pack_one(int e, const float* __restrict__ w, int stride, int koff,
                                         f16* __restrict__ hi, f16* __restrict__ lo) {
  int j = e & 7, lane = (e >> 3) & 63, ntg = (e >> 9) & 15, ks = e >> 13;
  int n = ntg * 16 + (lane & 15);
  int k = ks * 32 + 4 * (lane >> 4) + (j & 3) + 16 * (j >> 2);
  float v = w[(size_t)n * stride + koff + k];
  f16 h = (f16)v;
  f16 l = (f16)(v - (float)h);
  hi[e] = h; lo[e] = l;
}

__global__ __launch_bounds__(256) void k_pack(
    const float* __restrict__ w1, const float* __restrict__ w2,
    const float* __restrict__ w3, const float* __restrict__ w4,
    const float* __restrict__ w5, float* __restrict__ ws) {
  int t = blockIdx.x * 256 + threadIdx.x;
  if (t < 131072) {   // W4T / W5T fp32 transpose
    int m = t >> 16, v = t & 65535;
    int c = v >> 8, o = v & 255;
    const float* src = m ? w5 : w4;
    float* dst = ws + (m ? OFF_W5T : OFF_W4T);
    dst[v] = src[o * 256 + c];
    return;
  }
  int u = t - 131072;
  if (u < 65536) { pack_one(u, w1, 387, 128, (f16*)(ws + OFF_P1H), (f16*)(ws + OFF_P1L)); return; }
  u -= 65536;
  if (u < 65536) { pack_one(u, w2, 256, 0, (f16*)(ws + OFF_P2H), (f16*)(ws + OFF_P2L)); return; }
  u -= 65536;
  if (u < 65536) { pack_one(u, w3, 256, 0, (f16*)(ws + OFF_P3H), (f16*)(ws + OFF_P3L)); return; }
}

// ---------------- kernel 1: biasfold -> A1 (p1-part of mlp layer 1 folded in) ----------------
__global__ __launch_bounds__(128) void k_biasfold(
    const float* __restrict__ points1,
    const float* __restrict__ w1, const float* __restrict__ bb1,
    const float* __restrict__ g1, const float* __restrict__ be1,
    const float* __restrict__ w2, const float* __restrict__ bb2,
    const float* __restrict__ g2, const float* __restrict__ be2,
    const float* __restrict__ w3, const float* __restrict__ bb3,
    const float* __restrict__ g3, const float* __restrict__ be3,
    const float* __restrict__ w1mlp,
    float* __restrict__ A1out) {
  int blk = blockIdx.x;
  int b = blk / N1, n = blk % N1;
  int t = threadIdx.x;
  __shared__ float x0[LCH], x1s[HH], x2s[HH], x3s[HH];
  const float bnS = 1.0f / sqrtf(1.0f + 1e-5f);

  x0[t]       = points1[((size_t)b * LCH + t) * N1 + n];
  x0[t + 128] = points1[((size_t)b * LCH + t + 128) * N1 + n];
  __syncthreads();
  {
    float acc = 0.f;
    const float* wr = w1 + (size_t)t * LCH;
    #pragma unroll 4
    for (int c = 0; c < LCH; c++) acc += wr[c] * x0[c];
    acc += bb1[t * N1 + n];
    acc = acc * (g1[t] * bnS) + be1[t];
    x1s[t] = lrelu(acc);
  }
  __syncthreads();
  {
    float acc = 0.f;
    const float* wr = w2 + (size_t)t * HH;
    #pragma unroll 4
    for (int c = 0; c < HH; c++) acc += wr[c] * x1s[c];
    acc += bb2[t * N1 + n];
    acc = acc * (g2[t] * bnS) + be2[t];
    x2s[t] = lrelu(acc);
  }
  __syncthreads();
  {
    float acc = 0.f;
    const float* wr = w3 + (size_t)t * HH;
    #pragma unroll 4
    for (int c = 0; c < HH; c++) acc += wr[c] * x2s[c];
    acc += bb3[t * N1 + n];
    acc = acc * (g3[t] * bnS) + be3[t];
    x3s[t] = lrelu(acc);
  }
  __syncthreads();
  // A1[n] = sum_{c<128} W1mlp[n][c] * p1[c]  (k-independent part of mlp layer 1)
  #pragma unroll
  for (int rep = 0; rep < 2; rep++) {
    int o = t + rep * 128;
    const float* wr = w1mlp + (size_t)o * 387;
    float acc = 0.f;
    #pragma unroll 4
    for (int c = 0; c < HH; c++) acc += wr[c] * x3s[c];
    A1out[(size_t)blk * 256 + o] = acc;
  }
}

// ---------------- kernel 2: kNN (unchanged, passing) ----------------
__global__ __launch_bounds__(256) void k_knn(
    const float* __restrict__ xyz1, const float* __restrict__ xyz2,
    int* __restrict__ knn) {
  int blk = blockIdx.x;
  int b = blk / N1, n = blk % N1;
  int t = threadIdx.x;
  __shared__ float dist[N2];
  __shared__ float wvv[4];
  __shared__ int wii[4];

  float ax = xyz1[((size_t)b * 3 + 0) * N1 + n];
  float ay = xyz1[((size_t)b * 3 + 1) * N1 + n];
  float az = xyz1[((size_t)b * 3 + 2) * N1 + n];
  float xx1 = ax * ax + ay * ay + az * az;
  const float* X = xyz2 + (size_t)b * 3 * N2;

  for (int i = 0; i < 16; i++) {
    int j = t + i * 256;
    float px = X[j], py = X[N2 + j], pz = X[2 * N2 + j];
    float xx2 = px * px + py * py + pz * pz;
    float dot = ax * px + ay * py + az * pz;
    dist[j] = (xx1 + xx2) - 2.0f * dot;
  }
  __syncthreads();

  int* out = knn + (size_t)blk * KNN;
  for (int it = 0; it < KNN; it++) {
    float best = FLT_MAX;
    int bi = N2;
    for (int i = 0; i < 16; i++) {
      int j = t + i * 256;
      float v = dist[j];
      if (v < best) { best = v; bi = j; }
    }
    for (int off = 32; off; off >>= 1) {
      float ov = __shfl_down(best, off);
      int oi = __shfl_down(bi, off);
      if (ov < best || (ov == best && oi < bi)) { best = ov; bi = oi; }
    }
    int w = t >> 6;
    if ((t & 63) == 0) { wvv[w] = best; wii[w] = bi; }
    __syncthreads();
    if (t == 0) {
      float bv = wvv[0]; int bj = wii[0];
      for (int q = 1; q < 4; q++)
        if (wvv[q] < bv || (wvv[q] == bv && wii[q] < bj)) { bv = wvv[q]; bj = wii[q]; }
      out[it] = bj;
      dist[bj] = FLT_MAX;
    }
    __syncthreads();
  }
}

// ---------------- MFMA layer: M=32 x N=64 per wave, split-fp16, K=256 ----------------
// n-tiles processed in PAIRS to cap live B-fragment registers (~16 instead of 32).
__device__ __forceinline__ void run_layer32(
    const f16* __restrict__ BH, const f16* __restrict__ BL,
    const f16* Xh, const f16* Xl,
    int w, int lane, int r16, int g, f32x4 acc[2][4]) {
  for (int ks = 0; ks < 8; ks++) {
    int k0 = ks * 32 + 4 * g;
    f16x8 Ah[2], Al[2];
    #pragma unroll
    for (int mt = 0; mt < 2; mt++) {
      int base = (mt * 16 + r16) * KP + k0;
      f16x4 h0 = *(const f16x4*)(Xh + base);
      f16x4 h1 = *(const f16x4*)(Xh + base + 16);
      f16x4 l0 = *(const f16x4*)(Xl + base);
      f16x4 l1 = *(const f16x4*)(Xl + base + 16);
      Ah[mt] = __builtin_shufflevector(h0, h1, 0, 1, 2, 3, 4, 5, 6, 7);
      Al[mt] = __builtin_shufflevector(l0, l1, 0, 1, 2, 3, 4, 5, 6, 7);
    }
    #pragma unroll
    for (int half = 0; half < 2; half++) {
      f16x8 Bh[2], Bl[2];
      #pragma unroll
      for (int p = 0; p < 2; p++) {
        int nt = half * 2 + p;
        size_t fi = ((size_t)((ks * 16 + w * 4 + nt) * 64 + lane)) * 8;
        Bh[p] = *(const f16x8*)(BH + fi);
        Bl[p] = *(const f16x8*)(BL + fi);
      }
      #pragma unroll
      for (int mt = 0; mt < 2; mt++)
        #pragma unroll
        for (int p = 0; p < 2; p++) {
          int nt = half * 2 + p;
          acc[mt][nt] = __builtin_amdgcn_mfma_f32_16x16x32_f16(Ah[mt], Bh[p], acc[mt][nt], 0, 0, 0);
          acc[mt][nt] = __builtin_amdgcn_mfma_f32_16x16x32_f16(Ah[mt], Bl[p], acc[mt][nt], 0, 0, 0);
          acc[mt][nt] = __builtin_amdgcn_mfma_f32_16x16x32_f16(Al[mt], Bh[p], acc[mt][nt], 0, 0, 0);
        }
    }
  }
}

__device__ __forceinline__ void writeback_act(
    f32x4 acc[2][4], const float* __restrict__ bias,
    f16* Xh, f16* Xl, int w, int r16, int g) {
  #pragma unroll
  for (int nt = 0; nt < 4; nt++) {
    int nl = w * 64 + nt * 16 + r16;
    float bv = bias[nl];
    #pragma unroll
    for (int mt = 0; mt < 2; mt++)
      #pragma unroll
      for (int j = 0; j < 4; j++) {
        int m = mt * 16 + 4 * g + j;
        float y = lrelu(acc[mt][nt][j] + bv);
        f16 h = (f16)y;
        Xh[m * KP + nl] = h;
        Xl[m * KP + nl] = (f16)(y - (float)h);
      }
  }
}

// ---------------- kernel 3: fused gather + MFMA MLP + maxpool + mlp2 + regress ----------------
// NO min-waves launch bound: cap-induced spill (r3: 2.25 GB, r4: 2.13 GB scratch) costs far
// more than the occupancy it buys. r2 proved this pipeline compiles spill-free uncapped.
__global__ __launch_bounds__(256) void k_fused5(
    const float* __restrict__ xyz1, const float* __restrict__ xyz2,
    const float* __restrict__ points2,
    const float* __restrict__ A1ws, const int* __restrict__ knn,
    const float* __restrict__ w1mlp,
    const f16* __restrict__ P1H, const f16* __restrict__ P1L,
    const f16* __restrict__ P2H, const f16* __restrict__ P2L,
    const f16* __restrict__ P3H, const f16* __restrict__ P3L,
    const float* __restrict__ b1, const float* __restrict__ b2,
    const float* __restrict__ b3,
    const float* __restrict__ W4T, const float* __restrict__ W5T,
    const float* __restrict__ regw, const float* __restrict__ regb,
    float* __restrict__ out) {
  int bid = blockIdx.x;
  // XCD swizzle: all 21 n1-blocks of a batch land on one XCD (2688 = 8*336)
  int xcd = bid & 7, slot = bid >> 3;
  int b = xcd * 16 + slot / 21;
  int n1 = slot % 21;
  int row = b * N1 + n1;

  int t = threadIdx.x;
  int lane = t & 63, w = t >> 6;
  int r16 = lane & 15, g = lane >> 4;

  __shared__ __align__(16) f16 Xhi[32 * KP];
  __shared__ __align__(16) f16 Xlo[32 * KP];
  __shared__ float dirs[32][3];
  __shared__ int idxs[KNN];
  __shared__ float x1p[3];

  if (t < KNN) idxs[t] = knn[(size_t)row * KNN + t];
  if (t < 3) x1p[t] = xyz1[((size_t)b * 3 + t) * N1 + n1];
  __syncthreads();

  // per-lane constants: A1 + dir-part weights for this lane's 4 output columns
  float a1v[4], wd0[4], wd1[4], wd2[4];
  #pragma unroll
  for (int nt = 0; nt < 4; nt++) {
    int n = w * 64 + nt * 16 + r16;
    a1v[nt] = A1ws[(size_t)row * 256 + n];
    wd0[nt] = w1mlp[(size_t)n * 387 + 384];
    wd1[nt] = w1mlp[(size_t)n * 387 + 385];
    wd2[nt] = w1mlp[(size_t)n * 387 + 386];
  }

  float poolm[4] = {-FLT_MAX, -FLT_MAX, -FLT_MAX, -FLT_MAX};
  const float* p2b = points2 + (size_t)b * CC * N2;
  const float* x2b = xyz2 + (size_t)b * 3 * N2;

  for (int pass = 0; pass < 2; pass++) {
    // dirs for this pass's 32 neighbors
    if (t < 32) {
      int id = idxs[pass * 32 + t];
      #pragma unroll
      for (int d = 0; d < 3; d++)
        dirs[t][d] = x2b[(size_t)d * N2 + id] - x1p[d];
    }
    // gather g2: thread t -> row r = t>>3, channels c = (t&7) + 8i
    {
      int r = t >> 3, q = t & 7;
      int id = idxs[pass * 32 + r];
      const float* src = p2b + id;
      #pragma unroll 4
      for (int i = 0; i < 32; i++) {
        int c = q + 8 * i;
        float v = src[(size_t)c * N2];
        f16 h = (f16)v;
        Xhi[r * KP + c] = h;
        Xlo[r * KP + c] = (f16)(v - (float)h);
      }
    }
    __syncthreads();

    f32x4 acc[2][4];
    // ---- layer 1 (K=256 over g2), acc init = A1[n] + W1[n][384:387]·dir[m] ----
    #pragma unroll
    for (int mt = 0; mt < 2; mt++)
      #pragma unroll
      for (int nt = 0; nt < 4; nt++)
        #pragma unroll
        for (int j = 0; j < 4; j++) {
          int m = mt * 16 + 4 * g + j;
          acc[mt][nt][j] = a1v[nt] + wd0[nt] * dirs[m][0]
                                   + wd1[nt] * dirs[m][1]
                                   + wd2[nt] * dirs[m][2];
        }
    run_layer32(P1H, P1L, Xhi, Xlo, w, lane, r16, g, acc);
    __syncthreads();
    writeback_act(acc, b1, Xhi, Xlo, w, r16, g);
    __syncthreads();

    // ---- layer 2 ----
    #pragma unroll
    for (int mt = 0; mt < 2; mt++)
      #pragma unroll
      for (int nt = 0; nt < 4; nt++) acc[mt][nt] = (f32x4){0.f, 0.f, 0.f, 0.f};
    run_layer32(P2H, P2L, Xhi, Xlo, w, lane, r16, g, acc);
    __syncthreads();
    writeback_act(acc, b2, Xhi, Xlo, w, r16, g);
    __syncthreads();

    // ---- layer 3 + maxpool over this pass's 32 rows (bias/lrelu deferred) ----
    #pragma unroll
    for (int mt = 0; mt < 2; mt++)
      #pragma unroll
      for (int nt = 0; nt < 4; nt++) acc[mt][nt] = (f32x4){0.f, 0.f, 0.f, 0.f};
    run_layer32(P3H, P3L, Xhi, Xlo, w, lane, r16, g, acc);
    #pragma unroll
    for (int nt = 0; nt < 4; nt++) {
      float m = -FLT_MAX;
      #pragma unroll
      for (int mt = 0; mt < 2; mt++)
        #pragma unroll
        for (int j = 0; j < 4; j++) m = fmaxf(m, acc[mt][nt][j]);
      m = fmaxf(m, __shfl_xor(m, 16));
      m = fmaxf(m, __shfl_xor(m, 32));
      poolm[nt] = fmaxf(poolm[nt], m);
    }
    __syncthreads();   // X free for next pass / tail
  }

  // ---- tail: pooled -> mlp2 -> regress (fp32), X arena reused as float buffer ----
  float* fb = (float*)Xhi;   // [0:256) pooled, [256:512) z1, [512:768) z2
  if (g == 0) {
    #pragma unroll
    for (int nt = 0; nt < 4; nt++) {
      int n = w * 64 + nt * 16 + r16;
      fb[n] = lrelu(poolm[nt] + b3[n]);   // bias+lrelu commute with max
    }
  }
  __syncthreads();
  {
    float a = 0.f;
    #pragma unroll 4
    for (int c = 0; c < 256; c++) a += W4T[(size_t)c * 256 + t] * fb[c];
    fb[256 + t] = lrelu(a);
  }
  __syncthreads();
  {
    float a = 0.f;
    #pragma unroll 4
    for (int c = 0; c < 256; c++) a += W5T[(size_t)c * 256 + t] * fb[256 + c];
    fb[512 + t] = lrelu(a);
  }
  __syncthreads();
  if (t < 192) {
    int o = t >> 6;
    float a = 0.f;
    #pragma unroll
    for (int i = 0; i < 4; i++) {
      int c = (t & 63) + 64 * i;
      a += regw[o * 256 + c] * fb[512 + c];
    }
    #pragma unroll
    for (int off = 32; off; off >>= 1) a += __shfl_xor(a, off);
    if ((t & 63) == 0) out[((size_t)b * 3 + o) * N1 + n1] = a + regb[o];
  }
}

extern "C" void kernel_launch(void* const* d_in, const int* in_sizes, int n_in,
                              void* d_out, int out_size, void* d_ws, size_t ws_size,
                              hipStream_t stream) {
  const float* xyz1    = (const float*)d_in[0];
  const float* xyz2    = (const float*)d_in[1];
  const float* points1 = (const float*)d_in[2];
  const float* points2 = (const float*)d_in[3];
  const float* bf_w1 = (const float*)d_in[4],  *bf_b1 = (const float*)d_in[5];
  const float* bf_g1 = (const float*)d_in[6],  *bf_e1 = (const float*)d_in[7];
  const float* bf_w2 = (const float*)d_in[8],  *bf_b2 = (const float*)d_in[9];
  const float* bf_g2 = (const float*)d_in[10], *bf_e2 = (const float*)d_in[11];
  const float* bf_w3 = (const float*)d_in[12], *bf_b3 = (const float*)d_in[13];
  const float* bf_g3 = (const float*)d_in[14], *bf_e3 = (const float*)d_in[15];
  const float* mlp_w1 = (const float*)d_in[16], *mlp_b1 = (const float*)d_in[17];
  const float* mlp_w2 = (const float*)d_in[18], *mlp_b2 = (const float*)d_in[19];
  const float* mlp_w3 = (const float*)d_in[20], *mlp_b3 = (const float*)d_in[21];
  const float* mlp2_w1 = (const float*)d_in[22], *mlp2_w2 = (const float*)d_in[23];
  const float* reg_w = (const float*)d_in[24], *reg_b = (const float*)d_in[25];

  float* ws  = (float*)d_ws;
  float* A1  = ws + OFF_A1;
  int*   knn = (int*)(ws + OFF_KNN);

  float* out = (float*)d_out;
  int rows = BB * N1;  // 2688

  k_pack<<<1280, 256, 0, stream>>>(mlp_w1, mlp_w2, mlp_w3, mlp2_w1, mlp2_w2, ws);
  k_biasfold<<<rows, 128, 0, stream>>>(points1,
      bf_w1, bf_b1, bf_g1, bf_e1,
      bf_w2, bf_b2, bf_g2, bf_e2,
      bf_w3, bf_b3, bf_g3, bf_e3, mlp_w1, A1);
  k_knn<<<rows, 256, 0, stream>>>(xyz1, xyz2, knn);
  k_fused5<<<rows, 256, 0, stream>>>(xyz1, xyz2, points2, A1, knn, mlp_w1,
      (const f16*)(ws + OFF_P1H), (const f16*)(ws + OFF_P1L),
      (const f16*)(ws + OFF_P2H), (const f16*)(ws + OFF_P2L),
      (const f16*)(ws + OFF_P3H), (const f16*)(ws + OFF_P3L),
      mlp_b1, mlp_b2, mlp_b3,
      ws + OFF_W4T, ws + OFF_W5T, reg_w, reg_b, out);
}

// Round 6
// 913.037 us; speedup vs baseline: 2.5687x; 2.1337x over previous
//
#include <hip/hip_runtime.h>
#include <float.h>

#define BB 128
#define N1 21
#define N2 4096
#define CC 256   // C (points2 channels)
#define LCH 256  // LC
#define HH 128   // H
#define KNN 64
#define KP 268   // LDS X row stride in f16 (256 + pad; bank stride 6 mod 32)

typedef _Float16 f16;
typedef f16 f16x4 __attribute__((ext_vector_type(4)));
typedef f16 f16x8 __attribute__((ext_vector_type(8)));
typedef float f32x4 __attribute__((ext_vector_type(4)));

// ---- workspace layout (float units) ----
static const size_t OFF_A1  = 0;                                   // [2688][256] f32
static const size_t OFF_KNN = OFF_A1 + (size_t)BB * N1 * 256;      // [2688][64] int
static const size_t OFF_W4T = OFF_KNN + (size_t)BB * N1 * KNN;     // [256][256] f32
static const size_t OFF_W5T = OFF_W4T + 65536;
static const size_t OFF_P1H = OFF_W5T + 65536;                     // each pack: 65536 f16 = 32768 f32
static const size_t OFF_P1L = OFF_P1H + 32768;
static const size_t OFF_P2H = OFF_P1L + 32768;
static const size_t OFF_P2L = OFF_P2H + 32768;
static const size_t OFF_P3H = OFF_P2L + 32768;
static const size_t OFF_P3L = OFF_P3H + 32768;

__device__ __forceinline__ float lrelu(float x) { return x > 0.f ? x : 0.1f * x; }

// fragment k-mapping kappa(lane,j) = 4*(lane>>4) + (j&3) + 16*(j>>2), used for BOTH
// A and B packing -> k-permutation cancels in the dot product.

// ---------------- kernel 0: weight pack/split ----------------
__device__ __forceinline__ void pack_one(int e, const float* __restrict__ w, int stride, int koff,
                                         f16* __restrict__ hi, f16* __restrict__ lo) {
  int j = e & 7, lane = (e >> 3) & 63, ntg = (e >> 9) & 15, ks = e >> 13;
  int n = ntg * 16 + (lane & 15);
  int k = ks * 32 + 4 * (lane >> 4) + (j & 3) + 16 * (j >> 2);
  float v = w[(size_t)n * stride + koff + k];
  f16 h = (f16)v;
  f16 l = (f16)(v - (float)h);
  hi[e] = h; lo[e] = l;
}

__global__ __launch_bounds__(256) void k_pack(
    const float* __restrict__ w1, const float* __restrict__ w2,
    const float* __restrict__ w3, const float* __restrict__ w4,
    const float* __restrict__ w5, float* __restrict__ ws) {
  int t = blockIdx.x * 256 + threadIdx.x;
  if (t < 131072) {   // W4T / W5T fp32 transpose
    int m = t >> 16, v = t & 65535;
    int c = v >> 8, o = v & 255;
    const float* src = m ? w5 : w4;
    float* dst = ws + (m ? OFF_W5T : OFF_W4T);
    dst[v] = src[o * 256 + c];
    return;
  }
  int u = t - 131072;
  if (u < 65536) { pack_one(u, w1, 387, 128, (f16*)(ws + OFF_P1H), (f16*)(ws + OFF_P1L)); return; }
  u -= 65536;
  if (u < 65536) { pack_one(u, w2, 256, 0, (f16*)(ws + OFF_P2H), (f16*)(ws + OFF_P2L)); return; }
  u -= 65536;
  if (u < 65536) { pack_one(u, w3, 256, 0, (f16*)(ws + OFF_P3H), (f16*)(ws + OFF_P3L)); return; }
}

// ---------------- kernel 1: biasfold -> A1 (p1-part of mlp layer 1 folded in) ----------------
__global__ __launch_bounds__(128) void k_biasfold(
    const float* __restrict__ points1,
    const float* __restrict__ w1, const float* __restrict__ bb1,
    const float* __restrict__ g1, const float* __restrict__ be1,
    const float* __restrict__ w2, const float* __restrict__ bb2,
    const float* __restrict__ g2, const float* __restrict__ be2,
    const float* __restrict__ w3, const float* __restrict__ bb3,
    const float* __restrict__ g3, const float* __restrict__ be3,
    const float* __restrict__ w1mlp,
    float* __restrict__ A1out) {
  int blk = blockIdx.x;
  int b = blk / N1, n = blk % N1;
  int t = threadIdx.x;
  __shared__ float x0[LCH], x1s[HH], x2s[HH], x3s[HH];
  const float bnS = 1.0f / sqrtf(1.0f + 1e-5f);

  x0[t]       = points1[((size_t)b * LCH + t) * N1 + n];
  x0[t + 128] = points1[((size_t)b * LCH + t + 128) * N1 + n];
  __syncthreads();
  {
    float acc = 0.f;
    const float* wr = w1 + (size_t)t * LCH;
    #pragma unroll 4
    for (int c = 0; c < LCH; c++) acc += wr[c] * x0[c];
    acc += bb1[t * N1 + n];
    acc = acc * (g1[t] * bnS) + be1[t];
    x1s[t] = lrelu(acc);
  }
  __syncthreads();
  {
    float acc = 0.f;
    const float* wr = w2 + (size_t)t * HH;
    #pragma unroll 4
    for (int c = 0; c < HH; c++) acc += wr[c] * x1s[c];
    acc += bb2[t * N1 + n];
    acc = acc * (g2[t] * bnS) + be2[t];
    x2s[t] = lrelu(acc);
  }
  __syncthreads();
  {
    float acc = 0.f;
    const float* wr = w3 + (size_t)t * HH;
    #pragma unroll 4
    for (int c = 0; c < HH; c++) acc += wr[c] * x2s[c];
    acc += bb3[t * N1 + n];
    acc = acc * (g3[t] * bnS) + be3[t];
    x3s[t] = lrelu(acc);
  }
  __syncthreads();
  // A1[n] = sum_{c<128} W1mlp[n][c] * p1[c]  (k-independent part of mlp layer 1)
  #pragma unroll
  for (int rep = 0; rep < 2; rep++) {
    int o = t + rep * 128;
    const float* wr = w1mlp + (size_t)o * 387;
    float acc = 0.f;
    #pragma unroll 4
    for (int c = 0; c < HH; c++) acc += wr[c] * x3s[c];
    A1out[(size_t)blk * 256 + o] = acc;
  }
}

// ---------------- kernel 2: kNN (unchanged, passing) ----------------
__global__ __launch_bounds__(256) void k_knn(
    const float* __restrict__ xyz1, const float* __restrict__ xyz2,
    int* __restrict__ knn) {
  int blk = blockIdx.x;
  int b = blk / N1, n = blk % N1;
  int t = threadIdx.x;
  __shared__ float dist[N2];
  __shared__ float wvv[4];
  __shared__ int wii[4];

  float ax = xyz1[((size_t)b * 3 + 0) * N1 + n];
  float ay = xyz1[((size_t)b * 3 + 1) * N1 + n];
  float az = xyz1[((size_t)b * 3 + 2) * N1 + n];
  float xx1 = ax * ax + ay * ay + az * az;
  const float* X = xyz2 + (size_t)b * 3 * N2;

  for (int i = 0; i < 16; i++) {
    int j = t + i * 256;
    float px = X[j], py = X[N2 + j], pz = X[2 * N2 + j];
    float xx2 = px * px + py * py + pz * pz;
    float dot = ax * px + ay * py + az * pz;
    dist[j] = (xx1 + xx2) - 2.0f * dot;
  }
  __syncthreads();

  int* out = knn + (size_t)blk * KNN;
  for (int it = 0; it < KNN; it++) {
    float best = FLT_MAX;
    int bi = N2;
    for (int i = 0; i < 16; i++) {
      int j = t + i * 256;
      float v = dist[j];
      if (v < best) { best = v; bi = j; }
    }
    for (int off = 32; off; off >>= 1) {
      float ov = __shfl_down(best, off);
      int oi = __shfl_down(bi, off);
      if (ov < best || (ov == best && oi < bi)) { best = ov; bi = oi; }
    }
    int w = t >> 6;
    if ((t & 63) == 0) { wvv[w] = best; wii[w] = bi; }
    __syncthreads();
    if (t == 0) {
      float bv = wvv[0]; int bj = wii[0];
      for (int q = 1; q < 4; q++)
        if (wvv[q] < bv || (wvv[q] == bv && wii[q] < bj)) { bv = wvv[q]; bj = wii[q]; }
      out[it] = bj;
      dist[bj] = FLT_MAX;
    }
    __syncthreads();
  }
}

// ---------------- MFMA layer: M=32 x N=64 per wave, split-fp16, K=256 ----------------
// ks loop MUST stay rolled (#pragma unroll 1): full unroll makes the scheduler hoist
// all 8 k-steps' B-fragment loads -> >256 live VGPRs -> scratch spill (r3/r4/r5:
// 2.25/2.13/1.24 GB WRITE_SIZE). Rolled: live set ~100 regs, no spill (r2 pattern).
__device__ __forceinline__ void run_layer32(
    const f16* __restrict__ BH, const f16* __restrict__ BL,
    const f16* Xh, const f16* Xl,
    int w, int lane, int r16, int g, f32x4 acc[2][4]) {
  #pragma unroll 1
  for (int ks = 0; ks < 8; ks++) {
    int k0 = ks * 32 + 4 * g;
    f16x8 Ah[2], Al[2];
    #pragma unroll
    for (int mt = 0; mt < 2; mt++) {
      int base = (mt * 16 + r16) * KP + k0;
      f16x4 h0 = *(const f16x4*)(Xh + base);
      f16x4 h1 = *(const f16x4*)(Xh + base + 16);
      f16x4 l0 = *(const f16x4*)(Xl + base);
      f16x4 l1 = *(const f16x4*)(Xl + base + 16);
      Ah[mt] = __builtin_shufflevector(h0, h1, 0, 1, 2, 3, 4, 5, 6, 7);
      Al[mt] = __builtin_shufflevector(l0, l1, 0, 1, 2, 3, 4, 5, 6, 7);
    }
    #pragma unroll
    for (int half = 0; half < 2; half++) {
      f16x8 Bh[2], Bl[2];
      #pragma unroll
      for (int p = 0; p < 2; p++) {
        int nt = half * 2 + p;
        size_t fi = ((size_t)((ks * 16 + w * 4 + nt) * 64 + lane)) * 8;
        Bh[p] = *(const f16x8*)(BH + fi);
        Bl[p] = *(const f16x8*)(BL + fi);
      }
      #pragma unroll
      for (int mt = 0; mt < 2; mt++)
        #pragma unroll
        for (int p = 0; p < 2; p++) {
          int nt = half * 2 + p;
          acc[mt][nt] = __builtin_amdgcn_mfma_f32_16x16x32_f16(Ah[mt], Bh[p], acc[mt][nt], 0, 0, 0);
          acc[mt][nt] = __builtin_amdgcn_mfma_f32_16x16x32_f16(Ah[mt], Bl[p], acc[mt][nt], 0, 0, 0);
          acc[mt][nt] = __builtin_amdgcn_mfma_f32_16x16x32_f16(Al[mt], Bh[p], acc[mt][nt], 0, 0, 0);
        }
    }
  }
}

__device__ __forceinline__ void writeback_act(
    f32x4 acc[2][4], const float* __restrict__ bias,
    f16* Xh, f16* Xl, int w, int r16, int g) {
  #pragma unroll
  for (int nt = 0; nt < 4; nt++) {
    int nl = w * 64 + nt * 16 + r16;
    float bv = bias[nl];
    #pragma unroll
    for (int mt = 0; mt < 2; mt++)
      #pragma unroll
      for (int j = 0; j < 4; j++) {
        int m = mt * 16 + 4 * g + j;
        float y = lrelu(acc[mt][nt][j] + bv);
        f16 h = (f16)y;
        Xh[m * KP + nl] = h;
        Xl[m * KP + nl] = (f16)(y - (float)h);
      }
  }
}

// ---------------- kernel 3: fused gather + MFMA MLP + maxpool + mlp2 + regress ----------------
__global__ __launch_bounds__(256, 3) void k_fused6(
    const float* __restrict__ xyz1, const float* __restrict__ xyz2,
    const float* __restrict__ points2,
    const float* __restrict__ A1ws, const int* __restrict__ knn,
    const float* __restrict__ w1mlp,
    const f16* __restrict__ P1H, const f16* __restrict__ P1L,
    const f16* __restrict__ P2H, const f16* __restrict__ P2L,
    const f16* __restrict__ P3H, const f16* __restrict__ P3L,
    const float* __restrict__ b1, const float* __restrict__ b2,
    const float* __restrict__ b3,
    const float* __restrict__ W4T, const float* __restrict__ W5T,
    const float* __restrict__ regw, const float* __restrict__ regb,
    float* __restrict__ out) {
  int bid = blockIdx.x;
  // XCD swizzle: all 21 n1-blocks of a batch land on one XCD (2688 = 8*336)
  int xcd = bid & 7, slot = bid >> 3;
  int b = xcd * 16 + slot / 21;
  int n1 = slot % 21;
  int row = b * N1 + n1;

  int t = threadIdx.x;
  int lane = t & 63, w = t >> 6;
  int r16 = lane & 15, g = lane >> 4;

  __shared__ __align__(16) f16 Xhi[32 * KP];
  __shared__ __align__(16) f16 Xlo[32 * KP];
  __shared__ float dirs[32][3];
  __shared__ int idxs[KNN];
  __shared__ float x1p[3];

  if (t < KNN) idxs[t] = knn[(size_t)row * KNN + t];
  if (t < 3) x1p[t] = xyz1[((size_t)b * 3 + t) * N1 + n1];
  __syncthreads();

  // per-lane constants: A1 + dir-part weights for this lane's 4 output columns
  float a1v[4], wd0[4], wd1[4], wd2[4];
  #pragma unroll
  for (int nt = 0; nt < 4; nt++) {
    int n = w * 64 + nt * 16 + r16;
    a1v[nt] = A1ws[(size_t)row * 256 + n];
    wd0[nt] = w1mlp[(size_t)n * 387 + 384];
    wd1[nt] = w1mlp[(size_t)n * 387 + 385];
    wd2[nt] = w1mlp[(size_t)n * 387 + 386];
  }

  float poolm[4] = {-FLT_MAX, -FLT_MAX, -FLT_MAX, -FLT_MAX};
  const float* p2b = points2 + (size_t)b * CC * N2;
  const float* x2b = xyz2 + (size_t)b * 3 * N2;

  #pragma unroll 1
  for (int pass = 0; pass < 2; pass++) {
    // dirs for this pass's 32 neighbors
    if (t < 32) {
      int id = idxs[pass * 32 + t];
      #pragma unroll
      for (int d = 0; d < 3; d++)
        dirs[t][d] = x2b[(size_t)d * N2 + id] - x1p[d];
    }
    // gather g2: thread t -> row r = t>>3, channels c = (t&7) + 8i
    {
      int r = t >> 3, q = t & 7;
      int id = idxs[pass * 32 + r];
      const float* src = p2b + id;
      #pragma unroll 4
      for (int i = 0; i < 32; i++) {
        int c = q + 8 * i;
        float v = src[(size_t)c * N2];
        f16 h = (f16)v;
        Xhi[r * KP + c] = h;
        Xlo[r * KP + c] = (f16)(v - (float)h);
      }
    }
    __syncthreads();

    f32x4 acc[2][4];
    // ---- layer 1 (K=256 over g2), acc init = A1[n] + W1[n][384:387]·dir[m] ----
    #pragma unroll
    for (int mt = 0; mt < 2; mt++)
      #pragma unroll
      for (int nt = 0; nt < 4; nt++)
        #pragma unroll
        for (int j = 0; j < 4; j++) {
          int m = mt * 16 + 4 * g + j;
          acc[mt][nt][j] = a1v[nt] + wd0[nt] * dirs[m][0]
                                   + wd1[nt] * dirs[m][1]
                                   + wd2[nt] * dirs[m][2];
        }
    run_layer32(P1H, P1L, Xhi, Xlo, w, lane, r16, g, acc);
    __syncthreads();
    writeback_act(acc, b1, Xhi, Xlo, w, r16, g);
    __syncthreads();

    // ---- layer 2 ----
    #pragma unroll
    for (int mt = 0; mt < 2; mt++)
      #pragma unroll
      for (int nt = 0; nt < 4; nt++) acc[mt][nt] = (f32x4){0.f, 0.f, 0.f, 0.f};
    run_layer32(P2H, P2L, Xhi, Xlo, w, lane, r16, g, acc);
    __syncthreads();
    writeback_act(acc, b2, Xhi, Xlo, w, r16, g);
    __syncthreads();

    // ---- layer 3 + maxpool over this pass's 32 rows (bias/lrelu deferred) ----
    #pragma unroll
    for (int mt = 0; mt < 2; mt++)
      #pragma unroll
      for (int nt = 0; nt < 4; nt++) acc[mt][nt] = (f32x4){0.f, 0.f, 0.f, 0.f};
    run_layer32(P3H, P3L, Xhi, Xlo, w, lane, r16, g, acc);
    #pragma unroll
    for (int nt = 0; nt < 4; nt++) {
      float m = -FLT_MAX;
      #pragma unroll
      for (int mt = 0; mt < 2; mt++)
        #pragma unroll
        for (int j = 0; j < 4; j++) m = fmaxf(m, acc[mt][nt][j]);
      m = fmaxf(m, __shfl_xor(m, 16));
      m = fmaxf(m, __shfl_xor(m, 32));
      poolm[nt] = fmaxf(poolm[nt], m);
    }
    __syncthreads();   // X free for next pass / tail
  }

  // ---- tail: pooled -> mlp2 -> regress (fp32), X arena reused as float buffer ----
  float* fb = (float*)Xhi;   // [0:256) pooled, [256:512) z1, [512:768) z2
  if (g == 0) {
    #pragma unroll
    for (int nt = 0; nt < 4; nt++) {
      int n = w * 64 + nt * 16 + r16;
      fb[n] = lrelu(poolm[nt] + b3[n]);   // bias+lrelu commute with max
    }
  }
  __syncthreads();
  {
    float a = 0.f;
    #pragma unroll 4
    for (int c = 0; c < 256; c++) a += W4T[(size_t)c * 256 + t] * fb[c];
    fb[256 + t] = lrelu(a);
  }
  __syncthreads();
  {
    float a = 0.f;
    #pragma unroll 4
    for (int c = 0; c < 256; c++) a += W5T[(size_t)c * 256 + t] * fb[256 + c];
    fb[512 + t] = lrelu(a);
  }
  __syncthreads();
  if (t < 192) {
    int o = t >> 6;
    float a = 0.f;
    #pragma unroll
    for (int i = 0; i < 4; i++) {
      int c = (t & 63) + 64 * i;
      a += regw[o * 256 + c] * fb[512 + c];
    }
    #pragma unroll
    for (int off = 32; off; off >>= 1) a += __shfl_xor(a, off);
    if ((t & 63) == 0) out[((size_t)b * 3 + o) * N1 + n1] = a + regb[o];
  }
}

extern "C" void kernel_launch(void* const* d_in, const int* in_sizes, int n_in,
                              void* d_out, int out_size, void* d_ws, size_t ws_size,
                              hipStream_t stream) {
  const float* xyz1    = (const float*)d_in[0];
  const float* xyz2    = (const float*)d_in[1];
  const float* points1 = (const float*)d_in[2];
  const float* points2 = (const float*)d_in[3];
  const float* bf_w1 = (const float*)d_in[4],  *bf_b1 = (const float*)d_in[5];
  const float* bf_g1 = (const float*)d_in[6],  *bf_e1 = (const float*)d_in[7];
  const float* bf_w2 = (const float*)d_in[8],  *bf_b2 = (const float*)d_in[9];
  const float* bf_g2 = (const float*)d_in[10], *bf_e2 = (const float*)d_in[11];
  const float* bf_w3 = (const float*)d_in[12], *bf_b3 = (const float*)d_in[13];
  const float* bf_g3 = (const float*)d_in[14], *bf_e3 = (const float*)d_in[15];
  const float* mlp_w1 = (const float*)d_in[16], *mlp_b1 = (const float*)d_in[17];
  const float* mlp_w2 = (const float*)d_in[18], *mlp_b2 = (const float*)d_in[19];
  const float* mlp_w3 = (const float*)d_in[20], *mlp_b3 = (const float*)d_in[21];
  const float* mlp2_w1 = (const float*)d_in[22], *mlp2_w2 = (const float*)d_in[23];
  const float* reg_w = (const float*)d_in[24], *reg_b = (const float*)d_in[25];

  float* ws  = (float*)d_ws;
  float* A1  = ws + OFF_A1;
  int*   knn = (int*)(ws + OFF_KNN);

  float* out = (float*)d_out;
  int rows = BB * N1;  // 2688

  k_pack<<<1280, 256, 0, stream>>>(mlp_w1, mlp_w2, mlp_w3, mlp2_w1, mlp2_w2, ws);
  k_biasfold<<<rows, 128, 0, stream>>>(points1,
      bf_w1, bf_b1, bf_g1, bf_e1,
      bf_w2, bf_b2, bf_g2, bf_e2,
      bf_w3, bf_b3, bf_g3, bf_e3, mlp_w1, A1);
  k_knn<<<rows, 256, 0, stream>>>(xyz1, xyz2, knn);
  k_fused6<<<rows, 256, 0, stream>>>(xyz1, xyz2, points2, A1, knn, mlp_w1,
      (const f16*)(ws + OFF_P1H), (const f16*)(ws + OFF_P1L),
      (const f16*)(ws + OFF_P2H), (const f16*)(ws + OFF_P2L),
      (const f16*)(ws + OFF_P3H), (const f16*)(ws + OFF_P3L),
      mlp_b1, mlp_b2, mlp_b3,
      ws + OFF_W4T, ws + OFF_W5T, reg_w, reg_b, out);
}

// Round 7
// 893.884 us; speedup vs baseline: 2.6237x; 1.0214x over previous
//
#include <hip/hip_runtime.h>
#include <float.h>

#define BB 128
#define N1 21
#define N2 4096
#define CC 256   // C (points2 channels)
#define LCH 256  // LC
#define HH 128   // H
#define KNN 64
#define KP 268   // LDS X row stride in f16 (256 + pad; bank stride 6 mod 32)

typedef _Float16 f16;
typedef f16 f16x4 __attribute__((ext_vector_type(4)));
typedef f16 f16x8 __attribute__((ext_vector_type(8)));
typedef float f32x4 __attribute__((ext_vector_type(4)));

// ---- workspace layout (float units) ----
static const size_t OFF_A1  = 0;                                   // [2688][256] f32
static const size_t OFF_KNN = OFF_A1 + (size_t)BB * N1 * 256;      // [2688][64] int
static const size_t OFF_W4T = OFF_KNN + (size_t)BB * N1 * KNN;     // [256][256] f32
static const size_t OFF_W5T = OFF_W4T + 65536;
static const size_t OFF_P1H = OFF_W5T + 65536;                     // each pack: 65536 f16 = 32768 f32
static const size_t OFF_P1L = OFF_P1H + 32768;
static const size_t OFF_P2H = OFF_P1L + 32768;
static const size_t OFF_P2L = OFF_P2H + 32768;
static const size_t OFF_P3H = OFF_P2L + 32768;
static const size_t OFF_P3L = OFF_P3H + 32768;
static const size_t OFF_P2T = OFF_P3L + 32768;                     // [B][N2][C] u32 (hi|lo f16) = 512 MB

__device__ __forceinline__ float lrelu(float x) { return x > 0.f ? x : 0.1f * x; }
__device__ __forceinline__ f16 f16bits(unsigned short b) { f16 r; __builtin_memcpy(&r, &b, 2); return r; }
__device__ __forceinline__ unsigned short bits16(f16 h) { unsigned short r; __builtin_memcpy(&r, &h, 2); return r; }

// fragment k-mapping kappa(lane,j) = 4*(lane>>4) + (j&3) + 16*(j>>2), used for BOTH
// A and B packing -> k-permutation cancels in the dot product.

// ---------------- kernel 0: weight pack/split ----------------
__device__ __forceinline__ void pack_one(int e, const float* __restrict__ w, int stride, int koff,
                                         f16* __restrict__ hi, f16* __restrict__ lo) {
  int j = e & 7, lane = (e >> 3) & 63, ntg = (e >> 9) & 15, ks = e >> 13;
  int n = ntg * 16 + (lane & 15);
  int k = ks * 32 + 4 * (lane >> 4) + (j & 3) + 16 * (j >> 2);
  float v = w[(size_t)n * stride + koff + k];
  f16 h = (f16)v;
  f16 l = (f16)(v - (float)h);
  hi[e] = h; lo[e] = l;
}

__global__ __launch_bounds__(256) void k_pack(
    const float* __restrict__ w1, const float* __restrict__ w2,
    const float* __restrict__ w3, const float* __restrict__ w4,
    const float* __restrict__ w5, float* __restrict__ ws) {
  int t = blockIdx.x * 256 + threadIdx.x;
  if (t < 131072) {   // W4T / W5T fp32 transpose
    int m = t >> 16, v = t & 65535;
    int c = v >> 8, o = v & 255;
    const float* src = m ? w5 : w4;
    float* dst = ws + (m ? OFF_W5T : OFF_W4T);
    dst[v] = src[o * 256 + c];
    return;
  }
  int u = t - 131072;
  if (u < 65536) { pack_one(u, w1, 387, 128, (f16*)(ws + OFF_P1H), (f16*)(ws + OFF_P1L)); return; }
  u -= 65536;
  if (u < 65536) { pack_one(u, w2, 256, 0, (f16*)(ws + OFF_P2H), (f16*)(ws + OFF_P2L)); return; }
  u -= 65536;
  if (u < 65536) { pack_one(u, w3, 256, 0, (f16*)(ws + OFF_P3H), (f16*)(ws + OFF_P3L)); return; }
}

// ---------------- kernel 0b: points2 [B][C][N2] f32 -> P2T [B][N2][C] u32(hi|lo f16) ----------------
// LDS-tiled 64x64 transpose: both global read and write fully coalesced (256B/wave).
__global__ __launch_bounds__(256) void k_t2(
    const float* __restrict__ points2, unsigned int* __restrict__ p2t) {
  __shared__ unsigned int tile[64][65];   // +1 pad: lane-major column reads are 2-way (free)
  int bid = blockIdx.x;
  int b = bid >> 8;
  int rem = bid & 255;
  int n0 = (rem >> 2) << 6;   // 64 n2-block
  int c0 = (rem & 3) << 6;    // 64 c-block
  int t = threadIdx.x;
  int tl = t & 63, tg = t >> 6;   // lane-in-64, group 0..3

  const float* src = points2 + ((size_t)b * CC) * N2;
  #pragma unroll
  for (int i = 0; i < 16; i++) {
    int cl = tg * 16 + i;
    float v = src[(size_t)(c0 + cl) * N2 + n0 + tl];
    f16 h = (f16)v;
    f16 l = (f16)(v - (float)h);
    tile[cl][tl] = (unsigned int)bits16(h) | ((unsigned int)bits16(l) << 16);
  }
  __syncthreads();
  unsigned int* dst = p2t + ((size_t)b * N2) * CC;
  #pragma unroll
  for (int i = 0; i < 16; i++) {
    int nl = tg * 16 + i;
    dst[(size_t)(n0 + nl) * CC + c0 + tl] = tile[tl][nl];
  }
}

// ---------------- kernel 1: biasfold -> A1 (p1-part of mlp layer 1 folded in) ----------------
__global__ __launch_bounds__(128) void k_biasfold(
    const float* __restrict__ points1,
    const float* __restrict__ w1, const float* __restrict__ bb1,
    const float* __restrict__ g1, const float* __restrict__ be1,
    const float* __restrict__ w2, const float* __restrict__ bb2,
    const float* __restrict__ g2, const float* __restrict__ be2,
    const float* __restrict__ w3, const float* __restrict__ bb3,
    const float* __restrict__ g3, const float* __restrict__ be3,
    const float* __restrict__ w1mlp,
    float* __restrict__ A1out) {
  int blk = blockIdx.x;
  int b = blk / N1, n = blk % N1;
  int t = threadIdx.x;
  __shared__ float x0[LCH], x1s[HH], x2s[HH], x3s[HH];
  const float bnS = 1.0f / sqrtf(1.0f + 1e-5f);

  x0[t]       = points1[((size_t)b * LCH + t) * N1 + n];
  x0[t + 128] = points1[((size_t)b * LCH + t + 128) * N1 + n];
  __syncthreads();
  {
    float acc = 0.f;
    const float* wr = w1 + (size_t)t * LCH;
    #pragma unroll 4
    for (int c = 0; c < LCH; c++) acc += wr[c] * x0[c];
    acc += bb1[t * N1 + n];
    acc = acc * (g1[t] * bnS) + be1[t];
    x1s[t] = lrelu(acc);
  }
  __syncthreads();
  {
    float acc = 0.f;
    const float* wr = w2 + (size_t)t * HH;
    #pragma unroll 4
    for (int c = 0; c < HH; c++) acc += wr[c] * x1s[c];
    acc += bb2[t * N1 + n];
    acc = acc * (g2[t] * bnS) + be2[t];
    x2s[t] = lrelu(acc);
  }
  __syncthreads();
  {
    float acc = 0.f;
    const float* wr = w3 + (size_t)t * HH;
    #pragma unroll 4
    for (int c = 0; c < HH; c++) acc += wr[c] * x2s[c];
    acc += bb3[t * N1 + n];
    acc = acc * (g3[t] * bnS) + be3[t];
    x3s[t] = lrelu(acc);
  }
  __syncthreads();
  // A1[n] = sum_{c<128} W1mlp[n][c] * p1[c]  (k-independent part of mlp layer 1)
  #pragma unroll
  for (int rep = 0; rep < 2; rep++) {
    int o = t + rep * 128;
    const float* wr = w1mlp + (size_t)o * 387;
    float acc = 0.f;
    #pragma unroll 4
    for (int c = 0; c < HH; c++) acc += wr[c] * x3s[c];
    A1out[(size_t)blk * 256 + o] = acc;
  }
}

// ---------------- kernel 2: kNN (unchanged, passing) ----------------
__global__ __launch_bounds__(256) void k_knn(
    const float* __restrict__ xyz1, const float* __restrict__ xyz2,
    int* __restrict__ knn) {
  int blk = blockIdx.x;
  int b = blk / N1, n = blk % N1;
  int t = threadIdx.x;
  __shared__ float dist[N2];
  __shared__ float wvv[4];
  __shared__ int wii[4];

  float ax = xyz1[((size_t)b * 3 + 0) * N1 + n];
  float ay = xyz1[((size_t)b * 3 + 1) * N1 + n];
  float az = xyz1[((size_t)b * 3 + 2) * N1 + n];
  float xx1 = ax * ax + ay * ay + az * az;
  const float* X = xyz2 + (size_t)b * 3 * N2;

  for (int i = 0; i < 16; i++) {
    int j = t + i * 256;
    float px = X[j], py = X[N2 + j], pz = X[2 * N2 + j];
    float xx2 = px * px + py * py + pz * pz;
    float dot = ax * px + ay * py + az * pz;
    dist[j] = (xx1 + xx2) - 2.0f * dot;
  }
  __syncthreads();

  int* out = knn + (size_t)blk * KNN;
  for (int it = 0; it < KNN; it++) {
    float best = FLT_MAX;
    int bi = N2;
    for (int i = 0; i < 16; i++) {
      int j = t + i * 256;
      float v = dist[j];
      if (v < best) { best = v; bi = j; }
    }
    for (int off = 32; off; off >>= 1) {
      float ov = __shfl_down(best, off);
      int oi = __shfl_down(bi, off);
      if (ov < best || (ov == best && oi < bi)) { best = ov; bi = oi; }
    }
    int w = t >> 6;
    if ((t & 63) == 0) { wvv[w] = best; wii[w] = bi; }
    __syncthreads();
    if (t == 0) {
      float bv = wvv[0]; int bj = wii[0];
      for (int q = 1; q < 4; q++)
        if (wvv[q] < bv || (wvv[q] == bv && wii[q] < bj)) { bv = wvv[q]; bj = wii[q]; }
      out[it] = bj;
      dist[bj] = FLT_MAX;
    }
    __syncthreads();
  }
}

// ---------------- MFMA layer: M=32 x N=64 per wave, split-fp16, K=256 ----------------
// ks loop MUST stay rolled (#pragma unroll 1): full unroll makes the scheduler hoist
// all 8 k-steps' B-fragment loads -> >256 live VGPRs -> scratch spill (r3/r4/r5:
// 2.25/2.13/1.24 GB WRITE_SIZE). Rolled: live set ~100 regs, no spill (r2 pattern).
__device__ __forceinline__ void run_layer32(
    const f16* __restrict__ BH, const f16* __restrict__ BL,
    const f16* Xh, const f16* Xl,
    int w, int lane, int r16, int g, f32x4 acc[2][4]) {
  #pragma unroll 1
  for (int ks = 0; ks < 8; ks++) {
    int k0 = ks * 32 + 4 * g;
    f16x8 Ah[2], Al[2];
    #pragma unroll
    for (int mt = 0; mt < 2; mt++) {
      int base = (mt * 16 + r16) * KP + k0;
      f16x4 h0 = *(const f16x4*)(Xh + base);
      f16x4 h1 = *(const f16x4*)(Xh + base + 16);
      f16x4 l0 = *(const f16x4*)(Xl + base);
      f16x4 l1 = *(const f16x4*)(Xl + base + 16);
      Ah[mt] = __builtin_shufflevector(h0, h1, 0, 1, 2, 3, 4, 5, 6, 7);
      Al[mt] = __builtin_shufflevector(l0, l1, 0, 1, 2, 3, 4, 5, 6, 7);
    }
    #pragma unroll
    for (int half = 0; half < 2; half++) {
      f16x8 Bh[2], Bl[2];
      #pragma unroll
      for (int p = 0; p < 2; p++) {
        int nt = half * 2 + p;
        size_t fi = ((size_t)((ks * 16 + w * 4 + nt) * 64 + lane)) * 8;
        Bh[p] = *(const f16x8*)(BH + fi);
        Bl[p] = *(const f16x8*)(BL + fi);
      }
      #pragma unroll
      for (int mt = 0; mt < 2; mt++)
        #pragma unroll
        for (int p = 0; p < 2; p++) {
          int nt = half * 2 + p;
          acc[mt][nt] = __builtin_amdgcn_mfma_f32_16x16x32_f16(Ah[mt], Bh[p], acc[mt][nt], 0, 0, 0);
          acc[mt][nt] = __builtin_amdgcn_mfma_f32_16x16x32_f16(Ah[mt], Bl[p], acc[mt][nt], 0, 0, 0);
          acc[mt][nt] = __builtin_amdgcn_mfma_f32_16x16x32_f16(Al[mt], Bh[p], acc[mt][nt], 0, 0, 0);
        }
    }
  }
}

__device__ __forceinline__ void writeback_act(
    f32x4 acc[2][4], const float* __restrict__ bias,
    f16* Xh, f16* Xl, int w, int r16, int g) {
  #pragma unroll
  for (int nt = 0; nt < 4; nt++) {
    int nl = w * 64 + nt * 16 + r16;
    float bv = bias[nl];
    #pragma unroll
    for (int mt = 0; mt < 2; mt++)
      #pragma unroll
      for (int j = 0; j < 4; j++) {
        int m = mt * 16 + 4 * g + j;
        float y = lrelu(acc[mt][nt][j] + bv);
        f16 h = (f16)y;
        Xh[m * KP + nl] = h;
        Xl[m * KP + nl] = (f16)(y - (float)h);
      }
  }
}

// ---------------- kernel 3: fused gather + MFMA MLP + maxpool + mlp2 + regress ----------------
// TRANS=1: gather from point-major P2T (coalesced uint4, pre-split f16 hi/lo).
// TRANS=0: fallback gather from points2 [B][C][N2] (used when ws too small for P2T).
template <int TRANS>
__global__ __launch_bounds__(256, 3) void k_fused7(
    const float* __restrict__ xyz1, const float* __restrict__ xyz2,
    const float* __restrict__ points2, const unsigned int* __restrict__ p2t,
    const float* __restrict__ A1ws, const int* __restrict__ knn,
    const float* __restrict__ w1mlp,
    const f16* __restrict__ P1H, const f16* __restrict__ P1L,
    const f16* __restrict__ P2H, const f16* __restrict__ P2L,
    const f16* __restrict__ P3H, const f16* __restrict__ P3L,
    const float* __restrict__ b1, const float* __restrict__ b2,
    const float* __restrict__ b3,
    const float* __restrict__ W4T, const float* __restrict__ W5T,
    const float* __restrict__ regw, const float* __restrict__ regb,
    float* __restrict__ out) {
  int bid = blockIdx.x;
  // XCD swizzle: all 21 n1-blocks of a batch land on one XCD (2688 = 8*336)
  int xcd = bid & 7, slot = bid >> 3;
  int b = xcd * 16 + slot / 21;
  int n1 = slot % 21;
  int row = b * N1 + n1;

  int t = threadIdx.x;
  int lane = t & 63, w = t >> 6;
  int r16 = lane & 15, g = lane >> 4;

  __shared__ __align__(16) f16 Xhi[32 * KP];
  __shared__ __align__(16) f16 Xlo[32 * KP];
  __shared__ float dirs[32][3];
  __shared__ int idxs[KNN];
  __shared__ float x1p[3];

  if (t < KNN) idxs[t] = knn[(size_t)row * KNN + t];
  if (t < 3) x1p[t] = xyz1[((size_t)b * 3 + t) * N1 + n1];
  __syncthreads();

  // per-lane constants: A1 + dir-part weights for this lane's 4 output columns
  float a1v[4], wd0[4], wd1[4], wd2[4];
  #pragma unroll
  for (int nt = 0; nt < 4; nt++) {
    int n = w * 64 + nt * 16 + r16;
    a1v[nt] = A1ws[(size_t)row * 256 + n];
    wd0[nt] = w1mlp[(size_t)n * 387 + 384];
    wd1[nt] = w1mlp[(size_t)n * 387 + 385];
    wd2[nt] = w1mlp[(size_t)n * 387 + 386];
  }

  float poolm[4] = {-FLT_MAX, -FLT_MAX, -FLT_MAX, -FLT_MAX};
  const float* p2b = points2 + (size_t)b * CC * N2;
  const float* x2b = xyz2 + (size_t)b * 3 * N2;

  #pragma unroll 1
  for (int pass = 0; pass < 2; pass++) {
    // dirs for this pass's 32 neighbors
    if (t < 32) {
      int id = idxs[pass * 32 + t];
      #pragma unroll
      for (int d = 0; d < 3; d++)
        dirs[t][d] = x2b[(size_t)d * N2 + id] - x1p[d];
    }
    // gather g2 tile [32 rows][256 ch]
    if (TRANS) {
      int r = t >> 3, q = t & 7;
      int id = idxs[pass * 32 + r];
      const uint4* src = (const uint4*)(p2t + ((size_t)b * N2 + id) * CC + q * 32);
      uint4 v[8];
      #pragma unroll
      for (int i = 0; i < 8; i++) v[i] = src[i];   // 8 coalesced 16B loads in flight
      #pragma unroll
      for (int i = 0; i < 8; i++) {
        unsigned int a4[4] = {v[i].x, v[i].y, v[i].z, v[i].w};
        f16x4 hv, lv;
        #pragma unroll
        for (int j = 0; j < 4; j++) {
          hv[j] = f16bits((unsigned short)(a4[j] & 0xffffu));
          lv[j] = f16bits((unsigned short)(a4[j] >> 16));
        }
        int cpos = r * KP + q * 32 + i * 4;
        *(f16x4*)(Xhi + cpos) = hv;
        *(f16x4*)(Xlo + cpos) = lv;
      }
    } else {
      int r = t >> 3, q = t & 7;
      int id = idxs[pass * 32 + r];
      const float* src = p2b + id;
      #pragma unroll 4
      for (int i = 0; i < 32; i++) {
        int c = q + 8 * i;
        float v = src[(size_t)c * N2];
        f16 h = (f16)v;
        Xhi[r * KP + c] = h;
        Xlo[r * KP + c] = (f16)(v - (float)h);
      }
    }
    __syncthreads();

    f32x4 acc[2][4];
    // ---- layer 1 (K=256 over g2), acc init = A1[n] + W1[n][384:387]·dir[m] ----
    #pragma unroll
    for (int mt = 0; mt < 2; mt++)
      #pragma unroll
      for (int nt = 0; nt < 4; nt++)
        #pragma unroll
        for (int j = 0; j < 4; j++) {
          int m = mt * 16 + 4 * g + j;
          acc[mt][nt][j] = a1v[nt] + wd0[nt] * dirs[m][0]
                                   + wd1[nt] * dirs[m][1]
                                   + wd2[nt] * dirs[m][2];
        }
    run_layer32(P1H, P1L, Xhi, Xlo, w, lane, r16, g, acc);
    __syncthreads();
    writeback_act(acc, b1, Xhi, Xlo, w, r16, g);
    __syncthreads();

    // ---- layer 2 ----
    #pragma unroll
    for (int mt = 0; mt < 2; mt++)
      #pragma unroll
      for (int nt = 0; nt < 4; nt++) acc[mt][nt] = (f32x4){0.f, 0.f, 0.f, 0.f};
    run_layer32(P2H, P2L, Xhi, Xlo, w, lane, r16, g, acc);
    __syncthreads();
    writeback_act(acc, b2, Xhi, Xlo, w, r16, g);
    __syncthreads();

    // ---- layer 3 + maxpool over this pass's 32 rows (bias/lrelu deferred) ----
    #pragma unroll
    for (int mt = 0; mt < 2; mt++)
      #pragma unroll
      for (int nt = 0; nt < 4; nt++) acc[mt][nt] = (f32x4){0.f, 0.f, 0.f, 0.f};
    run_layer32(P3H, P3L, Xhi, Xlo, w, lane, r16, g, acc);
    #pragma unroll
    for (int nt = 0; nt < 4; nt++) {
      float m = -FLT_MAX;
      #pragma unroll
      for (int mt = 0; mt < 2; mt++)
        #pragma unroll
        for (int j = 0; j < 4; j++) m = fmaxf(m, acc[mt][nt][j]);
      m = fmaxf(m, __shfl_xor(m, 16));
      m = fmaxf(m, __shfl_xor(m, 32));
      poolm[nt] = fmaxf(poolm[nt], m);
    }
    __syncthreads();   // X free for next pass / tail
  }

  // ---- tail: pooled -> mlp2 -> regress (fp32), X arena reused as float buffer ----
  float* fb = (float*)Xhi;   // [0:256) pooled, [256:512) z1, [512:768) z2
  if (g == 0) {
    #pragma unroll
    for (int nt = 0; nt < 4; nt++) {
      int n = w * 64 + nt * 16 + r16;
      fb[n] = lrelu(poolm[nt] + b3[n]);   // bias+lrelu commute with max
    }
  }
  __syncthreads();
  {
    float a = 0.f;
    #pragma unroll 4
    for (int c = 0; c < 256; c++) a += W4T[(size_t)c * 256 + t] * fb[c];
    fb[256 + t] = lrelu(a);
  }
  __syncthreads();
  {
    float a = 0.f;
    #pragma unroll 4
    for (int c = 0; c < 256; c++) a += W5T[(size_t)c * 256 + t] * fb[256 + c];
    fb[512 + t] = lrelu(a);
  }
  __syncthreads();
  if (t < 192) {
    int o = t >> 6;
    float a = 0.f;
    #pragma unroll
    for (int i = 0; i < 4; i++) {
      int c = (t & 63) + 64 * i;
      a += regw[o * 256 + c] * fb[512 + c];
    }
    #pragma unroll
    for (int off = 32; off; off >>= 1) a += __shfl_xor(a, off);
    if ((t & 63) == 0) out[((size_t)b * 3 + o) * N1 + n1] = a + regb[o];
  }
}

extern "C" void kernel_launch(void* const* d_in, const int* in_sizes, int n_in,
                              void* d_out, int out_size, void* d_ws, size_t ws_size,
                              hipStream_t stream) {
  const float* xyz1    = (const float*)d_in[0];
  const float* xyz2    = (const float*)d_in[1];
  const float* points1 = (const float*)d_in[2];
  const float* points2 = (const float*)d_in[3];
  const float* bf_w1 = (const float*)d_in[4],  *bf_b1 = (const float*)d_in[5];
  const float* bf_g1 = (const float*)d_in[6],  *bf_e1 = (const float*)d_in[7];
  const float* bf_w2 = (const float*)d_in[8],  *bf_b2 = (const float*)d_in[9];
  const float* bf_g2 = (const float*)d_in[10], *bf_e2 = (const float*)d_in[11];
  const float* bf_w3 = (const float*)d_in[12], *bf_b3 = (const float*)d_in[13];
  const float* bf_g3 = (const float*)d_in[14], *bf_e3 = (const float*)d_in[15];
  const float* mlp_w1 = (const float*)d_in[16], *mlp_b1 = (const float*)d_in[17];
  const float* mlp_w2 = (const float*)d_in[18], *mlp_b2 = (const float*)d_in[19];
  const float* mlp_w3 = (const float*)d_in[20], *mlp_b3 = (const float*)d_in[21];
  const float* mlp2_w1 = (const float*)d_in[22], *mlp2_w2 = (const float*)d_in[23];
  const float* reg_w = (const float*)d_in[24], *reg_b = (const float*)d_in[25];

  float* ws  = (float*)d_ws;
  float* A1  = ws + OFF_A1;
  int*   knn = (int*)(ws + OFF_KNN);
  unsigned int* p2t = (unsigned int*)(ws + OFF_P2T);

  float* out = (float*)d_out;
  int rows = BB * N1;  // 2688

  // P2T needs 512 MB of ws; guard on ws_size (fallback = round-6 gather path).
  size_t need_bytes = (OFF_P2T + (size_t)BB * N2 * CC) * sizeof(float);
  bool use_trans = (ws_size >= need_bytes);

  k_pack<<<1280, 256, 0, stream>>>(mlp_w1, mlp_w2, mlp_w3, mlp2_w1, mlp2_w2, ws);
  if (use_trans)
    k_t2<<<BB * 256, 256, 0, stream>>>(points2, p2t);
  k_biasfold<<<rows, 128, 0, stream>>>(points1,
      bf_w1, bf_b1, bf_g1, bf_e1,
      bf_w2, bf_b2, bf_g2, bf_e2,
      bf_w3, bf_b3, bf_g3, bf_e3, mlp_w1, A1);
  k_knn<<<rows, 256, 0, stream>>>(xyz1, xyz2, knn);
  if (use_trans)
    k_fused7<1><<<rows, 256, 0, stream>>>(xyz1, xyz2, points2, p2t, A1, knn, mlp_w1,
        (const f16*)(ws + OFF_P1H), (const f16*)(ws + OFF_P1L),
        (const f16*)(ws + OFF_P2H), (const f16*)(ws + OFF_P2L),
        (const f16*)(ws + OFF_P3H), (const f16*)(ws + OFF_P3L),
        mlp_b1, mlp_b2, mlp_b3,
        ws + OFF_W4T, ws + OFF_W5T, reg_w, reg_b, out);
  else
    k_fused7<0><<<rows, 256, 0, stream>>>(xyz1, xyz2, points2, p2t, A1, knn, mlp_w1,
        (const f16*)(ws + OFF_P1H), (const f16*)(ws + OFF_P1L),
        (const f16*)(ws + OFF_P2H), (const f16*)(ws + OFF_P2L),
        (const f16*)(ws + OFF_P3H), (const f16*)(ws + OFF_P3L),
        mlp_b1, mlp_b2, mlp_b3,
        ws + OFF_W4T, ws + OFF_W5T, reg_w, reg_b, out);
}